// Round 11
// baseline (244.029 us; speedup 1.0000x reference)
//
#include <hip/hip_runtime.h>
#include <stdint.h>

#define DIMSZ 2048
#define NH 16
#define NKV 4
#define HD 128
#define BATCH 2
#define SEQ 2048
#define MROWS (BATCH*SEQ)          // 4096
#define NQKV (NH*HD + 2*NKV*HD)    // 3072

typedef unsigned short u16;
typedef float f32x4 __attribute__((ext_vector_type(4)));
typedef short short8 __attribute__((ext_vector_type(8)));
typedef __bf16 bf16x8 __attribute__((ext_vector_type(8)));
typedef unsigned short u16x4 __attribute__((ext_vector_type(4)));

__device__ __forceinline__ u16 f2bf(float f) {
  __bf16 h = (__bf16)f;           // native RNE convert
  return __builtin_bit_cast(u16, h);
}

__device__ __forceinline__ float bf2f(u16 h) {
  union { uint32_t u; float f; } v; v.u = ((uint32_t)h) << 16; return v.f;
}

__device__ __forceinline__ void async16(void* lds, const void* g) {
  __builtin_amdgcn_global_load_lds(
      (const __attribute__((address_space(1))) void*)(g),
      (__attribute__((address_space(3))) void*)(lds), 16, 0, 0);
}

__device__ __forceinline__ bf16x8 load_frag(const u16* p) {
  short8 v = *reinterpret_cast<const short8*>(p);
  return __builtin_bit_cast(bf16x8, v);
}

// ---------------- cast x fp32 -> bf16 ----------------
__global__ void cast_x_kernel(const float* __restrict__ x, u16* __restrict__ xb) {
  int i = (blockIdx.x * blockDim.x + threadIdx.x) * 4;
  float4 v = *reinterpret_cast<const float4*>(x + i);
  u16x4 o;
  o.x = f2bf(v.x); o.y = f2bf(v.y); o.z = f2bf(v.z); o.w = f2bf(v.w);
  *reinterpret_cast<u16x4*>(xb + i) = o;
}

// ------------- merged transpose-cast of all 4 weights -------------
__global__ __launch_bounds__(1024) void wtrans_all_kernel(const float* __restrict__ wq,
                                                          const float* __restrict__ wk,
                                                          const float* __restrict__ wv,
                                                          const float* __restrict__ wo,
                                                          u16* __restrict__ wtqkv,
                                                          u16* __restrict__ wto) {
  __shared__ float t[32][33];
  int y = blockIdx.y;
  const float* src; int srcN; u16* dst; int nbase;
  if (y < 64)      { src = wq; srcN = 2048; dst = wtqkv;                          nbase = y * 32; }
  else if (y < 80) { src = wk; srcN = 512;  dst = wtqkv + (size_t)2048 * 2048;    nbase = (y - 64) * 32; }
  else if (y < 96) { src = wv; srcN = 512;  dst = wtqkv + (size_t)2560 * 2048;    nbase = (y - 80) * 32; }
  else             { src = wo; srcN = 2048; dst = wto;                            nbase = (y - 96) * 32; }
  int k0 = blockIdx.x * 32;
  int tx = threadIdx.x, ty = threadIdx.y;
  t[ty][tx] = src[(size_t)(k0 + ty) * srcN + nbase + tx];
  __syncthreads();
  dst[(size_t)(nbase + ty) * 2048 + k0 + tx] = f2bf(t[tx][ty]);
}

// ---------------- 8-phase-style 256x256 GEMM (gemm1) ----------------
#define COMPUTE_PAIR(q)                                                              \
  {                                                                                  \
    bf16x8 af[2][2];                                                                 \
    _Pragma("unroll")                                                                \
    for (int m2 = 0; m2 < 2; ++m2)                                                   \
      _Pragma("unroll")                                                              \
      for (int kk = 0; kk < 2; ++kk)                                                 \
        af[m2][kk] = load_frag(&lds[buf][0][wm * 8192 +                              \
            (((q) * 2 + m2) * 16 + l16) * 64 + ((kk * 4 + lg) ^ (l16 & 7)) * 8]);    \
    __builtin_amdgcn_s_setprio(1);                                                   \
    _Pragma("unroll")                                                                \
    for (int m2 = 0; m2 < 2; ++m2)                                                   \
      _Pragma("unroll")                                                              \
      for (int ni = 0; ni < 4; ++ni)                                                 \
        _Pragma("unroll")                                                            \
        for (int kk = 0; kk < 2; ++kk)                                               \
          acc[(q) * 2 + m2][ni] = __builtin_amdgcn_mfma_f32_16x16x32_bf16(           \
              af[m2][kk], bper[ni][kk], acc[(q) * 2 + m2][ni], 0, 0, 0);             \
    __builtin_amdgcn_s_setprio(0);                                                   \
  }

template <bool BF16OUT>
__global__ __launch_bounds__(512, 2) void gemm8p_kernel(const u16* __restrict__ A,
                                                        const u16* __restrict__ BT,
                                                        void* __restrict__ Cp,
                                                        int M, int N, int K, int gx) {
  __shared__ u16 lds[2][2][16384];   // [buf][A/B][256 rows x 64] = 128 KiB
  const int tid = threadIdx.x;
  const int wave = tid >> 6, lane = tid & 63;
  const int l16 = lane & 15, lg = lane >> 4;
  const int wm = wave >> 2, wn = wave & 3;
  const int rloc = lane >> 3;
  const int sOff = ((lane & 7) ^ rloc) * 8;
  const int nwg = gridDim.x;
  const int swz = (blockIdx.x & 7) * (nwg >> 3) + (blockIdx.x >> 3);
  const int bm = (swz / gx) * 256, bn = (swz % gx) * 256;

  f32x4 acc[8][4] = {};

  auto stage = [&](int dstbuf, int x, int h, const u16* xp, int xr0, int kk0) {
#pragma unroll
    for (int j = 0; j < 2; ++j) {
      int c = j * 8 + wave;   // 0..15, 1KB chunk = 8 rows
      async16(&lds[dstbuf][x][h * 8192 + c * 512],
              xp + (size_t)(xr0 + h * 128 + c * 8 + rloc) * K + kk0 + sOff);
    }
  };

  stage(0, 0, 0, A, bm, 0);
  stage(0, 0, 1, A, bm, 0);
  stage(0, 1, 0, BT, bn, 0);
  stage(0, 1, 1, BT, bn, 0);

  const int NT = K >> 6;
  for (int kt = 0; kt < NT; ++kt) {
    const int buf = kt & 1, nbuf = buf ^ 1;
    const int k0n = (kt + 1) << 6;
    const bool pf = (kt + 1 < NT);
    bf16x8 bper[4][2];

    if (pf) {
      stage(nbuf, 0, 0, A, bm, k0n);
      asm volatile("s_waitcnt vmcnt(2)" ::: "memory");
    } else {
      asm volatile("s_waitcnt vmcnt(0)" ::: "memory");
    }
    __builtin_amdgcn_s_barrier();
    __builtin_amdgcn_sched_barrier(0);
#pragma unroll
    for (int ni = 0; ni < 4; ++ni)
#pragma unroll
      for (int kk = 0; kk < 2; ++kk)
        bper[ni][kk] = load_frag(&lds[buf][1][(wn >> 1) * 8192 +
            ((wn & 1) * 64 + ni * 16 + l16) * 64 + ((kk * 4 + lg) ^ (l16 & 7)) * 8]);
    COMPUTE_PAIR(0)
    if (pf) stage(nbuf, 0, 1, A, bm, k0n);
    __builtin_amdgcn_s_barrier();
    __builtin_amdgcn_sched_barrier(0);
    COMPUTE_PAIR(1)
    if (pf) stage(nbuf, 1, 0, BT, bn, k0n);
    __builtin_amdgcn_s_barrier();
    __builtin_amdgcn_sched_barrier(0);
    COMPUTE_PAIR(2)
    if (pf) stage(nbuf, 1, 1, BT, bn, k0n);
    __builtin_amdgcn_s_barrier();
    __builtin_amdgcn_sched_barrier(0);
    COMPUTE_PAIR(3)
    __builtin_amdgcn_s_barrier();
  }

#pragma unroll
  for (int mi = 0; mi < 8; ++mi)
#pragma unroll
    for (int ni = 0; ni < 4; ++ni)
#pragma unroll
      for (int r = 0; r < 4; ++r) {
        size_t idx = (size_t)(bm + wm * 128 + mi * 16 + lg * 4 + r) * N +
                     bn + wn * 64 + ni * 16 + l16;
        if (BF16OUT) ((u16*)Cp)[idx] = f2bf(acc[mi][ni][r]);
        else         ((float*)Cp)[idx] = acc[mi][ni][r];
      }
}

// ---------------- 8-phase-style 256x128 GEMM (gemm2, fp32 out) ----------------
#define COMPUTE_MB(q)                                                                \
  {                                                                                  \
    bf16x8 af[2];                                                                    \
    _Pragma("unroll")                                                                \
    for (int kk = 0; kk < 2; ++kk)                                                   \
      af[kk] = load_frag(&lds2[buf][(wm * 64 + (q) * 16 + l16) * 64 +                \
                                    ((kk * 4 + lg) ^ (l16 & 7)) * 8]);               \
    __builtin_amdgcn_s_setprio(1);                                                   \
    _Pragma("unroll")                                                                \
    for (int ni = 0; ni < 4; ++ni)                                                   \
      _Pragma("unroll")                                                              \
      for (int kk = 0; kk < 2; ++kk)                                                 \
        acc[(q)][ni] = __builtin_amdgcn_mfma_f32_16x16x32_bf16(                      \
            af[kk], bper[ni][kk], acc[(q)][ni], 0, 0, 0);                            \
    __builtin_amdgcn_s_setprio(0);                                                   \
  }

__global__ __launch_bounds__(512, 2) void gemm8p_n128_kernel(const u16* __restrict__ A,
                                                             const u16* __restrict__ BT,
                                                             float* __restrict__ C,
                                                             int M, int N, int K, int gx) {
  __shared__ u16 lds2[2][24576];   // [buf][A 256x64 | B 128x64] = 96 KiB
  const int tid = threadIdx.x;
  const int wave = tid >> 6, lane = tid & 63;
  const int l16 = lane & 15, lg = lane >> 4;
  const int wm = wave >> 1, wn = wave & 1;
  const int rloc = lane >> 3;
  const int sOff = ((lane & 7) ^ rloc) * 8;
  const int nwg = gridDim.x;
  const int swz = (blockIdx.x & 7) * (nwg >> 3) + (blockIdx.x >> 3);
  const int bm = (swz / gx) * 256, bn = (swz % gx) * 128;

  f32x4 acc[4][4] = {};

  auto stageA = [&](int dstbuf, int h, int kk0) {
#pragma unroll
    for (int j = 0; j < 2; ++j) {
      int c = j * 8 + wave;
      async16(&lds2[dstbuf][h * 8192 + c * 512],
              A + (size_t)(bm + h * 128 + c * 8 + rloc) * K + kk0 + sOff);
    }
  };
  auto stageB = [&](int dstbuf, int kk0) {
#pragma unroll
    for (int j = 0; j < 2; ++j) {
      int c = j * 8 + wave;
      async16(&lds2[dstbuf][16384 + c * 512],
              BT + (size_t)(bn + c * 8 + rloc) * K + kk0 + sOff);
    }
  };

  stageA(0, 0, 0);
  stageA(0, 1, 0);
  stageB(0, 0);

  const int NT = K >> 6;
  for (int kt = 0; kt < NT; ++kt) {
    const int buf = kt & 1, nbuf = buf ^ 1;
    const int k0n = (kt + 1) << 6;
    const bool pf = (kt + 1 < NT);
    bf16x8 bper[4][2];

    if (pf) {
      stageA(nbuf, 0, k0n);
      asm volatile("s_waitcnt vmcnt(2)" ::: "memory");
    } else {
      asm volatile("s_waitcnt vmcnt(0)" ::: "memory");
    }
    __builtin_amdgcn_s_barrier();
    __builtin_amdgcn_sched_barrier(0);
#pragma unroll
    for (int ni = 0; ni < 4; ++ni)
#pragma unroll
      for (int kk = 0; kk < 2; ++kk)
        bper[ni][kk] = load_frag(&lds2[buf][16384 +
            (wn * 64 + ni * 16 + l16) * 64 + ((kk * 4 + lg) ^ (l16 & 7)) * 8]);
    COMPUTE_MB(0)
    if (pf) stageA(nbuf, 1, k0n);
    __builtin_amdgcn_s_barrier();
    __builtin_amdgcn_sched_barrier(0);
    COMPUTE_MB(1)
    if (pf) stageB(nbuf, k0n);
    __builtin_amdgcn_s_barrier();
    __builtin_amdgcn_sched_barrier(0);
    COMPUTE_MB(2)
    __builtin_amdgcn_s_barrier();
    __builtin_amdgcn_sched_barrier(0);
    COMPUTE_MB(3)
    __builtin_amdgcn_s_barrier();
  }

#pragma unroll
  for (int mb = 0; mb < 4; ++mb)
#pragma unroll
    for (int ni = 0; ni < 4; ++ni)
#pragma unroll
      for (int r = 0; r < 4; ++r)
        C[(size_t)(bm + wm * 64 + mb * 16 + lg * 4 + r) * N +
          bn + wn * 64 + ni * 16 + l16] = acc[mb][ni][r];
}

// ---------------- RoPE + pack K only (bf16 in / bf16 out) ----------------
__global__ void rope_k_kernel(const u16* __restrict__ qkv, const float* __restrict__ fc,
                              const float* __restrict__ fs, u16* __restrict__ Kb) {
  int gi = blockIdx.x * blockDim.x + threadIdx.x; // (b*SEQ+s)*64 + i
  int i = gi & 63;
  int t = gi >> 6;          // b*SEQ + s
  int s = t & (SEQ - 1), b = t >> 11;
  int kh = blockIdx.y;
  float c = fc[s * 64 + i], sn = fs[s * 64 + i];
  uint32_t pr = *reinterpret_cast<const uint32_t*>(&qkv[(size_t)t * NQKV + NH * HD + kh * HD + 2 * i]);
  float tr = bf2f((u16)(pr & 0xffff)), ti = bf2f((u16)(pr >> 16));
  uint32_t w = (uint32_t)f2bf(tr * c - ti * sn) |
               ((uint32_t)f2bf(tr * sn + ti * c) << 16);
  *reinterpret_cast<uint32_t*>(&Kb[((size_t)(b * NKV + kh) * SEQ + s) * HD + 2 * i]) = w;
}

// ---------------- V transpose: qkv v-part [s][d] bf16 -> VT [d][s] bf16 ----------------
__global__ __launch_bounds__(1024) void vtrans_kernel(const u16* __restrict__ qkv,
                                                      u16* __restrict__ vt) {
  __shared__ u16 t[32][33];
  int s0 = blockIdx.x * 32, d0 = blockIdx.y * 32;
  int bk = blockIdx.z;
  int b = bk >> 2, kh = bk & 3;
  int tx = threadIdx.x, ty = threadIdx.y;
  t[ty][tx] = qkv[(size_t)(b * SEQ + s0 + ty) * NQKV + NH * HD + NKV * HD + kh * HD + d0 + tx];
  __syncthreads();
  vt[((size_t)(b * NKV + kh) * HD + d0 + ty) * SEQ + s0 + tx] = t[tx][ty];
}

// ---------------- causal flash attention (pipelined QK^T[kt+1] ∥ softmax[kt]) --
// grid (16, NH, BATCH), 256 threads. Block p handles q-tiles {31-p, p}.
// K staged 2 tiles ahead (K[j] -> Ks[j&1]), V 1 ahead. Within step kt the
// independent QK^T[kt+1] MFMAs interleave with softmax[kt] VALU (T15
// mechanism); PV[kt] closes the step. One __syncthreads per step (full
// drain); extra sync after prologue QK^T[0] protects Ks[0] staging at kt=0.
__global__ __launch_bounds__(256) void attn_kernel(const u16* __restrict__ qkv,
                                                   const float* __restrict__ fc,
                                                   const float* __restrict__ fs,
                                                   const u16* __restrict__ Kc,
                                                   const u16* __restrict__ VT,
                                                   u16* __restrict__ AO) {
  __shared__ u16 Ks[2][64 * 128];   // [key][d], swizzled
  __shared__ u16 Vs[2][128 * 64];   // [d][key], swizzled
  __shared__ u16 Ps[4][16 * 64];    // per-wave P tile [q][key], swizzled
  const int pairi = blockIdx.x;     // 0..15
  const int h = blockIdx.y, b = blockIdx.z;
  const int kvh = h >> 2;
  const int tid = threadIdx.x, wave = tid >> 6, lane = tid & 63;
  const int l16 = lane & 15, lg = lane >> 4;

  const u16* Kbase = Kc + (size_t)(b * NKV + kvh) * SEQ * HD;
  const u16* Vbase = VT + (size_t)(b * NKV + kvh) * HD * SEQ;

  bf16x8 onesf;
#pragma unroll
  for (int j = 0; j < 8; ++j) onesf[j] = __builtin_bit_cast(__bf16, (u16)0x3F80);

  int kOff[4], vOff[4], kDst[4], vDst[4];
#pragma unroll
  for (int i = 0; i < 4; ++i) {
    int chunk = i * 4 + wave;                 // 0..15
    int krow = chunk * 4 + (lane >> 4);       // 0..63
    kOff[i] = krow * HD + ((lane & 15) ^ (krow & 15)) * 8;
    kDst[i] = chunk * 512;
    int vrow = chunk * 8 + (lane >> 3);       // 0..127
    vOff[i] = vrow * SEQ + ((lane & 7) ^ (vrow & 7)) * 8;
    vDst[i] = chunk * 512;
  }

  // stage K-tile j into Ks[j&1] / V-tile j into Vs[j&1]
  auto stageK = [&](int j) {
    const u16* base = Kbase + (size_t)(j * 64) * HD;
    u16* dst = Ks[j & 1];
#pragma unroll
    for (int i = 0; i < 4; ++i) async16(&dst[kDst[i]], base + kOff[i]);
  };
  auto stageV = [&](int j) {
    const u16* base = Vbase + j * 64;
    u16* dst = Vs[j & 1];
#pragma unroll
    for (int i = 0; i < 4; ++i) async16(&dst[vDst[i]], base + vOff[i]);
  };

  for (int sel = 0; sel < 2; ++sel) {
    const int qblk = sel ? pairi : (31 - pairi);
    const int qrow0 = qblk * 64 + wave * 16;
    const int rq = qrow0 + l16;     // this lane's q row

    // ---- Q load + in-register RoPE ----
    const float qs = 0.12751689760098266f; // log2(e)/sqrt(128)
    const u16* Qrow = qkv + (size_t)(b * SEQ + rq) * NQKV + h * HD;
    const float* fcb = fc + (size_t)rq * 64;
    const float* fsb = fs + (size_t)rq * 64;
    bf16x8 qf[4];
#pragma unroll
    for (int c = 0; c < 4; ++c) {
      bf16x8 raw = load_frag(Qrow + c * 32 + lg * 8);
      float4 cc = *reinterpret_cast<const float4*>(fcb + c * 16 + lg * 4);
      float4 sv = *reinterpret_cast<const float4*>(fsb + c * 16 + lg * 4);
      bf16x8 q;
#pragma unroll
      for (int j = 0; j < 4; ++j) {
        float e = (float)raw[2 * j], od = (float)raw[2 * j + 1];
        float ce = (&cc.x)[j] * qs, se = (&sv.x)[j] * qs;
        q[2 * j]     = (__bf16)(e * ce - od * se);
        q[2 * j + 1] = (__bf16)(e * se + od * ce);
      }
      qf[c] = q;
    }

    // QK^T of tile j (swapped operands): s[cb][r] = S[key=j*64+cb*16+lg*4+r][q=l16]
    auto qkt = [&](f32x4* sx, const u16* Kbuf) {
      __builtin_amdgcn_s_setprio(1);
#pragma unroll
      for (int cb = 0; cb < 4; ++cb) {
#pragma unroll
        for (int c = 0; c < 4; ++c) {
          bf16x8 kf = load_frag(&Kbuf[(cb * 16 + l16) * 128 + (((c * 4 + lg) ^ l16) & 15) * 8]);
          sx[cb] = __builtin_amdgcn_mfma_f32_16x16x32_bf16(kf, qf[c], sx[cb], 0, 0, 0);
        }
      }
      __builtin_amdgcn_s_setprio(0);
    };
    auto maskdiag = [&](f32x4* sx, int k0) {
#pragma unroll
      for (int cb = 0; cb < 4; ++cb)
#pragma unroll
        for (int r = 0; r < 4; ++r) {
          int key = k0 + cb * 16 + lg * 4 + r;
          if (key > rq) sx[cb][r] = -1e30f;
        }
    };

    f32x4 o[8] = {};
    f32x4 lsum = {};
    float m = -3e38f;

    __syncthreads(); // all waves done with LDS from previous q-tile; Q loads drained
    stageK(0);
    stageV(0);
    if (qblk >= 1) stageK(1);
    __syncthreads(); // K0 (+K1), V0 resident for all waves

    f32x4 sprev[4] = {};
    qkt(sprev, Ks[0]);
    if (qblk == 0) maskdiag(sprev, 0);
    __syncthreads(); // all waves done reading Ks[0] before kt=0 stages K[2] into it

    for (int kt = 0; kt <= qblk; ++kt) {
      // issue next-tile staging early (latency hides under this step's compute)
      if (kt + 1 <= qblk) stageV(kt + 1);
      if (kt + 2 <= qblk) stageK(kt + 2);

      // QK^T[kt+1] — independent of softmax[kt]; scheduler interleaves them
      f32x4 scur[4] = {};
      const bool havenext = kt < qblk;
      if (havenext) {
        qkt(scur, Ks[(kt + 1) & 1]);
        if (kt + 1 == qblk) maskdiag(scur, (kt + 1) * 64);
      }

      // ---- softmax of sprev (tile kt) ----
      float v0 = fmaxf(fmaxf(fmaxf(sprev[0][0], sprev[0][1]), fmaxf(sprev[0][2], sprev[0][3])),
                       fmaxf(fmaxf(sprev[1][0], sprev[1][1]), fmaxf(sprev[1][2], sprev[1][3])));
      v0 = fmaxf(v0, fmaxf(fmaxf(fmaxf(sprev[2][0], sprev[2][1]), fmaxf(sprev[2][2], sprev[2][3])),
                           fmaxf(fmaxf(sprev[3][0], sprev[3][1]), fmaxf(sprev[3][2], sprev[3][3]))));
      v0 = fmaxf(v0, __shfl_xor(v0, 16));
      v0 = fmaxf(v0, __shfl_xor(v0, 32));

      bool need = v0 > m + 8.f;
      if (__any(need)) {
        float newm = fmaxf(m, v0);
        float sc = exp2f(m - newm);
        m = newm;
        float scR[4];
#pragma unroll
        for (int r = 0; r < 4; ++r) scR[r] = __shfl(sc, lg * 4 + r);
#pragma unroll
        for (int r = 0; r < 4; ++r) {
          lsum[r] *= scR[r];
#pragma unroll
          for (int db = 0; db < 8; ++db) o[db][r] *= scR[r];
        }
      }

#pragma unroll
      for (int cb = 0; cb < 4; ++cb) {
        uint32_t lo = (uint32_t)f2bf(exp2f(sprev[cb][0] - m)) |
                      ((uint32_t)f2bf(exp2f(sprev[cb][1] - m)) << 16);
        uint32_t hi = (uint32_t)f2bf(exp2f(sprev[cb][2] - m)) |
                      ((uint32_t)f2bf(exp2f(sprev[cb][3] - m)) << 16);
        int idx = (l16 * 64 + cb * 16 + lg * 4) ^ ((l16 & 7) << 3);
        uint64_t w = (uint64_t)lo | ((uint64_t)hi << 32);
        *reinterpret_cast<uint64_t*>(&Ps[wave][idx]) = w;
      }

      bf16x8 pf[2];
#pragma unroll
      for (int c = 0; c < 2; ++c)
        pf[c] = load_frag(&Ps[wave][(l16 * 64 + c * 32 + lg * 8) ^ ((l16 & 7) << 3)]);
      __builtin_amdgcn_s_setprio(1);
#pragma unroll
      for (int c = 0; c < 2; ++c)
        lsum = __builtin_amdgcn_mfma_f32_16x16x32_bf16(pf[c], onesf, lsum, 0, 0, 0);
      const u16* Vbuf = Vs[kt & 1];
#pragma unroll
      for (int db = 0; db < 8; ++db) {
#pragma unroll
        for (int c = 0; c < 2; ++c) {
          bf16x8 vf = load_frag(&Vbuf[(db * 16 + l16) * 64 + ((c * 4 + lg) ^ (l16 & 7)) * 8]);
          o[db] = __builtin_amdgcn_mfma_f32_16x16x32_bf16(pf[c], vf, o[db], 0, 0, 0);
        }
      }
      __builtin_amdgcn_s_setprio(0);

      if (havenext) {
#pragma unroll
        for (int cb = 0; cb < 4; ++cb) sprev[cb] = scur[cb];
      }
      __syncthreads(); // drains this step's staging; all waves done with read bufs
    }

#pragma unroll
    for (int r = 0; r < 4; ++r) {
      float inv = 1.f / lsum[r];
      int rqo = qrow0 + lg * 4 + r;
      size_t dst = ((size_t)(b * SEQ + rqo) * NH + h) * HD;
#pragma unroll
      for (int db = 0; db < 8; ++db)
        AO[dst + db * 16 + l16] = f2bf(o[db][r] * inv);
    }
  }
}

extern "C" void kernel_launch(void* const* d_in, const int* in_sizes, int n_in,
                              void* d_out, int out_size, void* d_ws, size_t ws_size,
                              hipStream_t stream) {
  (void)in_sizes; (void)n_in; (void)out_size; (void)ws_size;
  const float* x  = (const float*)d_in[0];
  const float* fc = (const float*)d_in[1];
  const float* fs = (const float*)d_in[2];
  const float* wq = (const float*)d_in[3];
  const float* wk = (const float*)d_in[4];
  const float* wv = (const float*)d_in[5];
  const float* wo = (const float*)d_in[6];
  float* out = (float*)d_out;

  char* ws = (char*)d_ws;
  u16*  xb    = (u16*)(ws);                      // 16,777,216
  u16*  wtqkv = (u16*)(ws + 16777216);           // 12,582,912
  u16*  wto   = (u16*)(ws + 29360128);           //  8,388,608
  u16*  qkv   = (u16*)(ws + 37748736);           // 25,165,824 (bf16)
  u16*  Kb    = (u16*)(ws + 62914560);           //  4,194,304
  u16*  VTb   = (u16*)(ws + 67108864);           //  4,194,304
  u16*  AOb   = (u16*)(ws + 71303168);           // 16,777,216

  cast_x_kernel<<<dim3(8192), dim3(256), 0, stream>>>(x, xb);
  wtrans_all_kernel<<<dim3(64, 160), dim3(32, 32), 0, stream>>>(wq, wk, wv, wo, wtqkv, wto);

  gemm8p_kernel<true><<<dim3(192), dim3(512), 0, stream>>>(xb, wtqkv, qkv, MROWS, NQKV, DIMSZ, 12);

  rope_k_kernel<<<dim3(1024, 4), dim3(256), 0, stream>>>(qkv, fc, fs, Kb);
  vtrans_kernel<<<dim3(64, 4, 8), dim3(32, 32), 0, stream>>>(qkv, VTb);

  attn_kernel<<<dim3(16, 16, 2), dim3(256), 0, stream>>>(qkv, fc, fs, Kb, VTb, AOb);

  gemm8p_n128_kernel<<<dim3(256), dim3(512), 0, stream>>>(AOb, wto, out, MROWS, DIMSZ, DIMSZ, 16);
}

// Round 13
// 220.971 us; speedup vs baseline: 1.1044x; 1.1044x over previous
//
#include <hip/hip_runtime.h>
#include <stdint.h>

#define DIMSZ 2048
#define NH 16
#define NKV 4
#define HD 128
#define BATCH 2
#define SEQ 2048
#define MROWS (BATCH*SEQ)          // 4096
#define NQKV (NH*HD + 2*NKV*HD)    // 3072

typedef unsigned short u16;
typedef float f32x4 __attribute__((ext_vector_type(4)));
typedef short short8 __attribute__((ext_vector_type(8)));
typedef __bf16 bf16x8 __attribute__((ext_vector_type(8)));
typedef unsigned short u16x4 __attribute__((ext_vector_type(4)));

__device__ __forceinline__ u16 f2bf(float f) {
  __bf16 h = (__bf16)f;           // native RNE convert
  return __builtin_bit_cast(u16, h);
}

__device__ __forceinline__ float bf2f(u16 h) {
  union { uint32_t u; float f; } v; v.u = ((uint32_t)h) << 16; return v.f;
}

__device__ __forceinline__ void async16(void* lds, const void* g) {
  __builtin_amdgcn_global_load_lds(
      (const __attribute__((address_space(1))) void*)(g),
      (__attribute__((address_space(3))) void*)(lds), 16, 0, 0);
}

__device__ __forceinline__ bf16x8 load_frag(const u16* p) {
  short8 v = *reinterpret_cast<const short8*>(p);
  return __builtin_bit_cast(bf16x8, v);
}

// ---------------- cast x fp32 -> bf16 ----------------
__global__ void cast_x_kernel(const float* __restrict__ x, u16* __restrict__ xb) {
  int i = (blockIdx.x * blockDim.x + threadIdx.x) * 4;
  float4 v = *reinterpret_cast<const float4*>(x + i);
  u16x4 o;
  o.x = f2bf(v.x); o.y = f2bf(v.y); o.z = f2bf(v.z); o.w = f2bf(v.w);
  *reinterpret_cast<u16x4*>(xb + i) = o;
}

// ------------- merged transpose-cast of all 4 weights -------------
__global__ __launch_bounds__(1024) void wtrans_all_kernel(const float* __restrict__ wq,
                                                          const float* __restrict__ wk,
                                                          const float* __restrict__ wv,
                                                          const float* __restrict__ wo,
                                                          u16* __restrict__ wtqkv,
                                                          u16* __restrict__ wto) {
  __shared__ float t[32][33];
  int y = blockIdx.y;
  const float* src; int srcN; u16* dst; int nbase;
  if (y < 64)      { src = wq; srcN = 2048; dst = wtqkv;                          nbase = y * 32; }
  else if (y < 80) { src = wk; srcN = 512;  dst = wtqkv + (size_t)2048 * 2048;    nbase = (y - 64) * 32; }
  else if (y < 96) { src = wv; srcN = 512;  dst = wtqkv + (size_t)2560 * 2048;    nbase = (y - 80) * 32; }
  else             { src = wo; srcN = 2048; dst = wto;                            nbase = (y - 96) * 32; }
  int k0 = blockIdx.x * 32;
  int tx = threadIdx.x, ty = threadIdx.y;
  t[ty][tx] = src[(size_t)(k0 + ty) * srcN + nbase + tx];
  __syncthreads();
  dst[(size_t)(nbase + ty) * 2048 + k0 + tx] = f2bf(t[tx][ty]);
}

// ---------------- 8-phase 256x192 GEMM (gemm1, bf16 out) ----------------
// grid 16x16 = 256 blocks = 1/CU. 8 waves as 2M x 4N: wave tile 128x48,
// acc[8][3]. BK=64, LDS 112KB (A 2x32K, B 2x24K). Per K-tile: 4 phases
// {stage unit | raw s_barrier+sched_barrier | ds_read | MFMA setprio-wrapped};
// counted vmcnt(2) at phase 0 (only A-h0(kt+1)'s 2 loads newer than tile kt);
// 7 loads/thread per tile (A-h0:2, A-h1:2, B:3); iter-end barrier.
#define COMPUTE_PAIR3(q)                                                             \
  {                                                                                  \
    bf16x8 af[2][2];                                                                 \
    _Pragma("unroll")                                                                \
    for (int m2 = 0; m2 < 2; ++m2)                                                   \
      _Pragma("unroll")                                                              \
      for (int kk = 0; kk < 2; ++kk)                                                 \
        af[m2][kk] = load_frag(&ldsA[buf][wm * 8192 +                                \
            (((q) * 2 + m2) * 16 + l16) * 64 + ((kk * 4 + lg) ^ (l16 & 7)) * 8]);    \
    __builtin_amdgcn_s_setprio(1);                                                   \
    _Pragma("unroll")                                                                \
    for (int m2 = 0; m2 < 2; ++m2)                                                   \
      _Pragma("unroll")                                                              \
      for (int ni = 0; ni < 3; ++ni)                                                 \
        _Pragma("unroll")                                                            \
        for (int kk = 0; kk < 2; ++kk)                                               \
          acc[(q) * 2 + m2][ni] = __builtin_amdgcn_mfma_f32_16x16x32_bf16(           \
              af[m2][kk], bper[ni][kk], acc[(q) * 2 + m2][ni], 0, 0, 0);             \
    __builtin_amdgcn_s_setprio(0);                                                   \
  }

__global__ __launch_bounds__(512, 1) void gemm8p_n192_kernel(const u16* __restrict__ A,
                                                             const u16* __restrict__ BT,
                                                             u16* __restrict__ C,
                                                             int M, int N, int K, int gx) {
  __shared__ u16 ldsA[2][16384];   // 256 rows x 64, 32KB each buf
  __shared__ u16 ldsB[2][12288];   // 192 rows x 64, 24KB each buf
  const int tid = threadIdx.x;
  const int wave = tid >> 6, lane = tid & 63;
  const int l16 = lane & 15, lg = lane >> 4;
  const int wm = wave >> 2, wn = wave & 3;
  const int rloc = lane >> 3;
  const int sOff = ((lane & 7) ^ rloc) * 8;
  const int nwg = gridDim.x;
  const int swz = (blockIdx.x & 7) * (nwg >> 3) + (blockIdx.x >> 3);
  const int bm = (swz / gx) * 256, bn = (swz % gx) * 192;

  f32x4 acc[8][3] = {};

  auto stageA = [&](int dstbuf, int h, int kk0) {
#pragma unroll
    for (int j = 0; j < 2; ++j) {
      int c = j * 8 + wave;   // 0..15, 1KB chunk = 8 rows
      async16(&ldsA[dstbuf][h * 8192 + c * 512],
              A + (size_t)(bm + h * 128 + c * 8 + rloc) * K + kk0 + sOff);
    }
  };
  auto stageB = [&](int dstbuf, int kk0) {
#pragma unroll
    for (int j = 0; j < 3; ++j) {
      int c = j * 8 + wave;   // 0..23, 1KB chunk = 8 rows
      async16(&ldsB[dstbuf][c * 512],
              BT + (size_t)(bn + c * 8 + rloc) * K + kk0 + sOff);
    }
  };

  // prologue: tile 0 -> buf 0 (7 loads/thread outstanding)
  stageA(0, 0, 0);
  stageA(0, 1, 0);
  stageB(0, 0);

  const int NT = K >> 6;
  for (int kt = 0; kt < NT; ++kt) {
    const int buf = kt & 1, nbuf = buf ^ 1;
    const int k0n = (kt + 1) << 6;
    const bool pf = (kt + 1 < NT);
    bf16x8 bper[3][2];

    // phase 0: stage A-h0(kt+1); wait tile kt resident; B-frags + mi 0,1
    if (pf) {
      stageA(nbuf, 0, k0n);
      asm volatile("s_waitcnt vmcnt(2)" ::: "memory");
    } else {
      asm volatile("s_waitcnt vmcnt(0)" ::: "memory");
    }
    __builtin_amdgcn_s_barrier();
    __builtin_amdgcn_sched_barrier(0);
#pragma unroll
    for (int ni = 0; ni < 3; ++ni)
#pragma unroll
      for (int kk = 0; kk < 2; ++kk)
        bper[ni][kk] = load_frag(&ldsB[buf][
            (wn * 48 + ni * 16 + l16) * 64 + ((kk * 4 + lg) ^ (l16 & 7)) * 8]);
    COMPUTE_PAIR3(0)
    // phase 1: stage A-h1(kt+1); mi 2,3
    if (pf) stageA(nbuf, 1, k0n);
    __builtin_amdgcn_s_barrier();
    __builtin_amdgcn_sched_barrier(0);
    COMPUTE_PAIR3(1)
    // phase 2: stage B(kt+1); mi 4,5
    if (pf) stageB(nbuf, k0n);
    __builtin_amdgcn_s_barrier();
    __builtin_amdgcn_sched_barrier(0);
    COMPUTE_PAIR3(2)
    // phase 3: mi 6,7
    __builtin_amdgcn_s_barrier();
    __builtin_amdgcn_sched_barrier(0);
    COMPUTE_PAIR3(3)
    __builtin_amdgcn_s_barrier();
  }

#pragma unroll
  for (int mi = 0; mi < 8; ++mi)
#pragma unroll
    for (int ni = 0; ni < 3; ++ni)
#pragma unroll
      for (int r = 0; r < 4; ++r) {
        size_t idx = (size_t)(bm + wm * 128 + mi * 16 + lg * 4 + r) * N +
                     bn + wn * 48 + ni * 16 + l16;
        C[idx] = f2bf(acc[mi][ni][r]);
      }
}

// ---------------- 8-phase-style 256x128 GEMM (gemm2, fp32 out) ----------------
#define COMPUTE_MB(q)                                                                \
  {                                                                                  \
    bf16x8 af[2];                                                                    \
    _Pragma("unroll")                                                                \
    for (int kk = 0; kk < 2; ++kk)                                                   \
      af[kk] = load_frag(&lds2[buf][(wm * 64 + (q) * 16 + l16) * 64 +                \
                                    ((kk * 4 + lg) ^ (l16 & 7)) * 8]);               \
    __builtin_amdgcn_s_setprio(1);                                                   \
    _Pragma("unroll")                                                                \
    for (int ni = 0; ni < 4; ++ni)                                                   \
      _Pragma("unroll")                                                              \
      for (int kk = 0; kk < 2; ++kk)                                                 \
        acc[(q)][ni] = __builtin_amdgcn_mfma_f32_16x16x32_bf16(                      \
            af[kk], bper[ni][kk], acc[(q)][ni], 0, 0, 0);                            \
    __builtin_amdgcn_s_setprio(0);                                                   \
  }

__global__ __launch_bounds__(512, 2) void gemm8p_n128_kernel(const u16* __restrict__ A,
                                                             const u16* __restrict__ BT,
                                                             float* __restrict__ C,
                                                             int M, int N, int K, int gx) {
  __shared__ u16 lds2[2][24576];   // [buf][A 256x64 | B 128x64] = 96 KiB
  const int tid = threadIdx.x;
  const int wave = tid >> 6, lane = tid & 63;
  const int l16 = lane & 15, lg = lane >> 4;
  const int wm = wave >> 1, wn = wave & 1;
  const int rloc = lane >> 3;
  const int sOff = ((lane & 7) ^ rloc) * 8;
  const int nwg = gridDim.x;
  const int swz = (blockIdx.x & 7) * (nwg >> 3) + (blockIdx.x >> 3);
  const int bm = (swz / gx) * 256, bn = (swz % gx) * 128;

  f32x4 acc[4][4] = {};

  auto stageA = [&](int dstbuf, int h, int kk0) {
#pragma unroll
    for (int j = 0; j < 2; ++j) {
      int c = j * 8 + wave;
      async16(&lds2[dstbuf][h * 8192 + c * 512],
              A + (size_t)(bm + h * 128 + c * 8 + rloc) * K + kk0 + sOff);
    }
  };
  auto stageB = [&](int dstbuf, int kk0) {
#pragma unroll
    for (int j = 0; j < 2; ++j) {
      int c = j * 8 + wave;
      async16(&lds2[dstbuf][16384 + c * 512],
              BT + (size_t)(bn + c * 8 + rloc) * K + kk0 + sOff);
    }
  };

  stageA(0, 0, 0);
  stageA(0, 1, 0);
  stageB(0, 0);

  const int NT = K >> 6;
  for (int kt = 0; kt < NT; ++kt) {
    const int buf = kt & 1, nbuf = buf ^ 1;
    const int k0n = (kt + 1) << 6;
    const bool pf = (kt + 1 < NT);
    bf16x8 bper[4][2];

    if (pf) {
      stageA(nbuf, 0, k0n);
      asm volatile("s_waitcnt vmcnt(2)" ::: "memory");
    } else {
      asm volatile("s_waitcnt vmcnt(0)" ::: "memory");
    }
    __builtin_amdgcn_s_barrier();
    __builtin_amdgcn_sched_barrier(0);
#pragma unroll
    for (int ni = 0; ni < 4; ++ni)
#pragma unroll
      for (int kk = 0; kk < 2; ++kk)
        bper[ni][kk] = load_frag(&lds2[buf][16384 +
            (wn * 64 + ni * 16 + l16) * 64 + ((kk * 4 + lg) ^ (l16 & 7)) * 8]);
    COMPUTE_MB(0)
    if (pf) stageA(nbuf, 1, k0n);
    __builtin_amdgcn_s_barrier();
    __builtin_amdgcn_sched_barrier(0);
    COMPUTE_MB(1)
    if (pf) stageB(nbuf, k0n);
    __builtin_amdgcn_s_barrier();
    __builtin_amdgcn_sched_barrier(0);
    COMPUTE_MB(2)
    __builtin_amdgcn_s_barrier();
    __builtin_amdgcn_sched_barrier(0);
    COMPUTE_MB(3)
    __builtin_amdgcn_s_barrier();
  }

#pragma unroll
  for (int mb = 0; mb < 4; ++mb)
#pragma unroll
    for (int ni = 0; ni < 4; ++ni)
#pragma unroll
      for (int r = 0; r < 4; ++r)
        C[(size_t)(bm + wm * 64 + mb * 16 + lg * 4 + r) * N +
          bn + wn * 64 + ni * 16 + l16] = acc[mb][ni][r];
}

// ---------------- RoPE + pack K only (bf16 in / bf16 out) ----------------
__global__ void rope_k_kernel(const u16* __restrict__ qkv, const float* __restrict__ fc,
                              const float* __restrict__ fs, u16* __restrict__ Kb) {
  int gi = blockIdx.x * blockDim.x + threadIdx.x; // (b*SEQ+s)*64 + i
  int i = gi & 63;
  int t = gi >> 6;          // b*SEQ + s
  int s = t & (SEQ - 1), b = t >> 11;
  int kh = blockIdx.y;
  float c = fc[s * 64 + i], sn = fs[s * 64 + i];
  uint32_t pr = *reinterpret_cast<const uint32_t*>(&qkv[(size_t)t * NQKV + NH * HD + kh * HD + 2 * i]);
  float tr = bf2f((u16)(pr & 0xffff)), ti = bf2f((u16)(pr >> 16));
  uint32_t w = (uint32_t)f2bf(tr * c - ti * sn) |
               ((uint32_t)f2bf(tr * sn + ti * c) << 16);
  *reinterpret_cast<uint32_t*>(&Kb[((size_t)(b * NKV + kh) * SEQ + s) * HD + 2 * i]) = w;
}

// ---------------- V transpose: qkv v-part [s][d] bf16 -> VT [d][s] bf16 ----------------
__global__ __launch_bounds__(1024) void vtrans_kernel(const u16* __restrict__ qkv,
                                                      u16* __restrict__ vt) {
  __shared__ u16 t[32][33];
  int s0 = blockIdx.x * 32, d0 = blockIdx.y * 32;
  int bk = blockIdx.z;
  int b = bk >> 2, kh = bk & 3;
  int tx = threadIdx.x, ty = threadIdx.y;
  t[ty][tx] = qkv[(size_t)(b * SEQ + s0 + ty) * NQKV + NH * HD + NKV * HD + kh * HD + d0 + tx];
  __syncthreads();
  vt[((size_t)(b * NKV + kh) * HD + d0 + ty) * SEQ + s0 + tx] = t[tx][ty];
}

// ---------------- causal flash attention (round-10: swapped QK^T + defer-max) --
__global__ __launch_bounds__(256) void attn_kernel(const u16* __restrict__ qkv,
                                                   const float* __restrict__ fc,
                                                   const float* __restrict__ fs,
                                                   const u16* __restrict__ Kc,
                                                   const u16* __restrict__ VT,
                                                   u16* __restrict__ AO) {
  __shared__ u16 Ks[2][64 * 128];   // [key][d], swizzled
  __shared__ u16 Vs[2][128 * 64];   // [d][key], swizzled
  __shared__ u16 Ps[4][16 * 64];    // per-wave P tile [q][key], swizzled
  const int pairi = blockIdx.x;     // 0..15
  const int h = blockIdx.y, b = blockIdx.z;
  const int kvh = h >> 2;
  const int tid = threadIdx.x, wave = tid >> 6, lane = tid & 63;
  const int l16 = lane & 15, lg = lane >> 4;

  const u16* Kbase = Kc + (size_t)(b * NKV + kvh) * SEQ * HD;
  const u16* Vbase = VT + (size_t)(b * NKV + kvh) * HD * SEQ;

  bf16x8 onesf;
#pragma unroll
  for (int j = 0; j < 8; ++j) onesf[j] = __builtin_bit_cast(__bf16, (u16)0x3F80);

  int kOff[4], vOff[4], kDst[4], vDst[4];
#pragma unroll
  for (int i = 0; i < 4; ++i) {
    int chunk = i * 4 + wave;                 // 0..15
    int krow = chunk * 4 + (lane >> 4);       // 0..63
    kOff[i] = krow * HD + ((lane & 15) ^ (krow & 15)) * 8;
    kDst[i] = chunk * 512;
    int vrow = chunk * 8 + (lane >> 3);       // 0..127
    vOff[i] = vrow * SEQ + ((lane & 7) ^ (vrow & 7)) * 8;
    vDst[i] = chunk * 512;
  }

  for (int sel = 0; sel < 2; ++sel) {
    const int qblk = sel ? pairi : (31 - pairi);
    const int qrow0 = qblk * 64 + wave * 16;
    const int rq = qrow0 + l16;     // this lane's q row

    // ---- Q load + in-register RoPE ----
    const float qs = 0.12751689760098266f; // log2(e)/sqrt(128)
    const u16* Qrow = qkv + (size_t)(b * SEQ + rq) * NQKV + h * HD;
    const float* fcb = fc + (size_t)rq * 64;
    const float* fsb = fs + (size_t)rq * 64;
    bf16x8 qf[4];
#pragma unroll
    for (int c = 0; c < 4; ++c) {
      bf16x8 raw = load_frag(Qrow + c * 32 + lg * 8);
      float4 cc = *reinterpret_cast<const float4*>(fcb + c * 16 + lg * 4);
      float4 sv = *reinterpret_cast<const float4*>(fsb + c * 16 + lg * 4);
      bf16x8 q;
#pragma unroll
      for (int j = 0; j < 4; ++j) {
        float e = (float)raw[2 * j], od = (float)raw[2 * j + 1];
        float ce = (&cc.x)[j] * qs, se = (&sv.x)[j] * qs;
        q[2 * j]     = (__bf16)(e * ce - od * se);
        q[2 * j + 1] = (__bf16)(e * se + od * ce);
      }
      qf[c] = q;
    }

    f32x4 o[8] = {};
    f32x4 lsum = {};
    float m = -3e38f;

    __syncthreads(); // all waves done with LDS from previous q-tile
#pragma unroll
    for (int i = 0; i < 4; ++i) {
      async16(&Ks[0][kDst[i]], Kbase + kOff[i]);
      async16(&Vs[0][vDst[i]], Vbase + vOff[i]);
    }

    for (int kt = 0; kt <= qblk; ++kt) {
      const int cur = kt & 1;
      __syncthreads(); // tile kt staged; all waves done with buf[cur]
      if (kt < qblk) {
        const int k0n = (kt + 1) * 64;
#pragma unroll
        for (int i = 0; i < 4; ++i) {
          async16(&Ks[cur ^ 1][kDst[i]], Kbase + (size_t)k0n * HD + kOff[i]);
          async16(&Vs[cur ^ 1][vDst[i]], Vbase + k0n + vOff[i]);
        }
      }

      // QK^T swapped: s[cb][r] = S[key = k0+cb*16+lg*4+r][q = l16]
      f32x4 s[4] = {};
      __builtin_amdgcn_s_setprio(1);
#pragma unroll
      for (int cb = 0; cb < 4; ++cb) {
#pragma unroll
        for (int c = 0; c < 4; ++c) {
          bf16x8 kf = load_frag(&Ks[cur][(cb * 16 + l16) * 128 + (((c * 4 + lg) ^ l16) & 15) * 8]);
          s[cb] = __builtin_amdgcn_mfma_f32_16x16x32_bf16(kf, qf[c], s[cb], 0, 0, 0);
        }
      }
      __builtin_amdgcn_s_setprio(0);

      if (kt == qblk) { // diagonal tile: causal mask
        const int k0 = kt * 64;
#pragma unroll
        for (int cb = 0; cb < 4; ++cb) {
#pragma unroll
          for (int r = 0; r < 4; ++r) {
            int key = k0 + cb * 16 + lg * 4 + r;
            if (key > rq) s[cb][r] = -1e30f;
          }
        }
      }

      // per-lane tile max (q = l16)
      float v0 = fmaxf(fmaxf(fmaxf(s[0][0], s[0][1]), fmaxf(s[0][2], s[0][3])),
                       fmaxf(fmaxf(s[1][0], s[1][1]), fmaxf(s[1][2], s[1][3])));
      v0 = fmaxf(v0, fmaxf(fmaxf(fmaxf(s[2][0], s[2][1]), fmaxf(s[2][2], s[2][3])),
                           fmaxf(fmaxf(s[3][0], s[3][1]), fmaxf(s[3][2], s[3][3]))));
      v0 = fmaxf(v0, __shfl_xor(v0, 16));
      v0 = fmaxf(v0, __shfl_xor(v0, 32));

      bool need = v0 > m + 8.f;
      if (__any(need)) {
        float newm = fmaxf(m, v0);
        float sc = exp2f(m - newm);
        m = newm;
        float scR[4];
#pragma unroll
        for (int r = 0; r < 4; ++r) scR[r] = __shfl(sc, lg * 4 + r);
#pragma unroll
        for (int r = 0; r < 4; ++r) {
          lsum[r] *= scR[r];
#pragma unroll
          for (int db = 0; db < 8; ++db) o[db][r] *= scR[r];
        }
      }

      // exp2 + pack + one b64 write per cb (keys cb*16+lg*4..+3, row q=l16)
#pragma unroll
      for (int cb = 0; cb < 4; ++cb) {
        uint32_t lo = (uint32_t)f2bf(exp2f(s[cb][0] - m)) |
                      ((uint32_t)f2bf(exp2f(s[cb][1] - m)) << 16);
        uint32_t hi = (uint32_t)f2bf(exp2f(s[cb][2] - m)) |
                      ((uint32_t)f2bf(exp2f(s[cb][3] - m)) << 16);
        int idx = (l16 * 64 + cb * 16 + lg * 4) ^ ((l16 & 7) << 3);
        uint64_t w = (uint64_t)lo | ((uint64_t)hi << 32);
        *reinterpret_cast<uint64_t*>(&Ps[wave][idx]) = w;
      }

      bf16x8 pf[2];
#pragma unroll
      for (int c = 0; c < 2; ++c)
        pf[c] = load_frag(&Ps[wave][(l16 * 64 + c * 32 + lg * 8) ^ ((l16 & 7) << 3)]);
      __builtin_amdgcn_s_setprio(1);
#pragma unroll
      for (int c = 0; c < 2; ++c)
        lsum = __builtin_amdgcn_mfma_f32_16x16x32_bf16(pf[c], onesf, lsum, 0, 0, 0);
#pragma unroll
      for (int db = 0; db < 8; ++db) {
#pragma unroll
        for (int c = 0; c < 2; ++c) {
          bf16x8 vf = load_frag(&Vs[cur][(db * 16 + l16) * 64 + ((c * 4 + lg) ^ (l16 & 7)) * 8]);
          o[db] = __builtin_amdgcn_mfma_f32_16x16x32_bf16(pf[c], vf, o[db], 0, 0, 0);
        }
      }
      __builtin_amdgcn_s_setprio(0);
    }

#pragma unroll
    for (int r = 0; r < 4; ++r) {
      float inv = 1.f / lsum[r];
      int rqo = qrow0 + lg * 4 + r;
      size_t dst = ((size_t)(b * SEQ + rqo) * NH + h) * HD;
#pragma unroll
      for (int db = 0; db < 8; ++db)
        AO[dst + db * 16 + l16] = f2bf(o[db][r] * inv);
    }
  }
}

extern "C" void kernel_launch(void* const* d_in, const int* in_sizes, int n_in,
                              void* d_out, int out_size, void* d_ws, size_t ws_size,
                              hipStream_t stream) {
  (void)in_sizes; (void)n_in; (void)out_size; (void)ws_size;
  const float* x  = (const float*)d_in[0];
  const float* fc = (const float*)d_in[1];
  const float* fs = (const float*)d_in[2];
  const float* wq = (const float*)d_in[3];
  const float* wk = (const float*)d_in[4];
  const float* wv = (const float*)d_in[5];
  const float* wo = (const float*)d_in[6];
  float* out = (float*)d_out;

  char* ws = (char*)d_ws;
  u16*  xb    = (u16*)(ws);                      // 16,777,216
  u16*  wtqkv = (u16*)(ws + 16777216);           // 12,582,912
  u16*  wto   = (u16*)(ws + 29360128);           //  8,388,608
  u16*  qkv   = (u16*)(ws + 37748736);           // 25,165,824 (bf16)
  u16*  Kb    = (u16*)(ws + 62914560);           //  4,194,304
  u16*  VTb   = (u16*)(ws + 67108864);           //  4,194,304
  u16*  AOb   = (u16*)(ws + 71303168);           // 16,777,216

  cast_x_kernel<<<dim3(8192), dim3(256), 0, stream>>>(x, xb);
  wtrans_all_kernel<<<dim3(64, 160), dim3(32, 32), 0, stream>>>(wq, wk, wv, wo, wtqkv, wto);

  gemm8p_n192_kernel<<<dim3(256), dim3(512), 0, stream>>>(xb, wtqkv, qkv, MROWS, NQKV, DIMSZ, 16);

  rope_k_kernel<<<dim3(1024, 4), dim3(256), 0, stream>>>(qkv, fc, fs, Kb);
  vtrans_kernel<<<dim3(64, 4, 8), dim3(32, 32), 0, stream>>>(qkv, VTb);

  attn_kernel<<<dim3(16, 16, 2), dim3(256), 0, stream>>>(qkv, fc, fs, Kb, VTb, AOb);

  gemm8p_n128_kernel<<<dim3(256), dim3(512), 0, stream>>>(AOb, wto, out, MROWS, DIMSZ, DIMSZ, 16);
}

// Round 14
// 197.395 us; speedup vs baseline: 1.2362x; 1.1194x over previous
//
#include <hip/hip_runtime.h>
#include <stdint.h>

#define DIMSZ 2048
#define NH 16
#define NKV 4
#define HD 128
#define BATCH 2
#define SEQ 2048
#define MROWS (BATCH*SEQ)          // 4096
#define NQKV (NH*HD + 2*NKV*HD)    // 3072

typedef unsigned short u16;
typedef float f32x4 __attribute__((ext_vector_type(4)));
typedef short short8 __attribute__((ext_vector_type(8)));
typedef __bf16 bf16x8 __attribute__((ext_vector_type(8)));
typedef unsigned short u16x4 __attribute__((ext_vector_type(4)));
typedef unsigned short u16x8 __attribute__((ext_vector_type(8)));

__device__ __forceinline__ u16 f2bf(float f) {
  __bf16 h = (__bf16)f;           // native RNE convert
  return __builtin_bit_cast(u16, h);
}

__device__ __forceinline__ float bf2f(u16 h) {
  union { uint32_t u; float f; } v; v.u = ((uint32_t)h) << 16; return v.f;
}

__device__ __forceinline__ void async16(void* lds, const void* g) {
  __builtin_amdgcn_global_load_lds(
      (const __attribute__((address_space(1))) void*)(g),
      (__attribute__((address_space(3))) void*)(lds), 16, 0, 0);
}

__device__ __forceinline__ bf16x8 load_frag(const u16* p) {
  short8 v = *reinterpret_cast<const short8*>(p);
  return __builtin_bit_cast(bf16x8, v);
}

// ---------------- cast x fp32 -> bf16 ----------------
__global__ void cast_x_kernel(const float* __restrict__ x, u16* __restrict__ xb) {
  int i = (blockIdx.x * blockDim.x + threadIdx.x) * 4;
  float4 v = *reinterpret_cast<const float4*>(x + i);
  u16x4 o;
  o.x = f2bf(v.x); o.y = f2bf(v.y); o.z = f2bf(v.z); o.w = f2bf(v.w);
  *reinterpret_cast<u16x4*>(xb + i) = o;
}

// ------------- vectorized merged transpose-cast of all 4 weights -------------
// 64x64 tiles, 256 threads: float4 global loads (256B bursts), LDS [64][65]
// (+1 pad => <=2-way banks both phases), u16x8 stores (128B bursts).
// grid (32, 80): y<32 wq | y<40 wk | y<48 wv | else wo.
__global__ __launch_bounds__(256) void wtrans64_kernel(const float* __restrict__ wq,
                                                       const float* __restrict__ wk,
                                                       const float* __restrict__ wv,
                                                       const float* __restrict__ wo,
                                                       u16* __restrict__ wtqkv,
                                                       u16* __restrict__ wto) {
  __shared__ float tb[64][65];
  int y = blockIdx.y;
  const float* src; int srcN; u16* dst; int nbase;
  if (y < 32)      { src = wq; srcN = 2048; dst = wtqkv;                        nbase = y * 64; }
  else if (y < 40) { src = wk; srcN = 512;  dst = wtqkv + (size_t)2048 * 2048;  nbase = (y - 32) * 64; }
  else if (y < 48) { src = wv; srcN = 512;  dst = wtqkv + (size_t)2560 * 2048;  nbase = (y - 40) * 64; }
  else             { src = wo; srcN = 2048; dst = wto;                          nbase = (y - 48) * 64; }
  int k0 = blockIdx.x * 64;
  int t = threadIdx.x;
  int lr = t >> 4, lc = (t & 15) * 4;
#pragma unroll
  for (int i = 0; i < 4; ++i) {
    int row = lr + i * 16;
    float4 v = *reinterpret_cast<const float4*>(&src[(size_t)(k0 + row) * srcN + nbase + lc]);
    tb[row][lc] = v.x; tb[row][lc + 1] = v.y; tb[row][lc + 2] = v.z; tb[row][lc + 3] = v.w;
  }
  __syncthreads();
  int n = t >> 3, kg = (t & 7) * 8;
#pragma unroll
  for (int i = 0; i < 2; ++i) {
    int nn = n + i * 32;
    u16x8 o;
#pragma unroll
    for (int j = 0; j < 8; ++j) o[j] = f2bf(tb[kg + j][nn]);
    *reinterpret_cast<u16x8*>(&dst[(size_t)(nbase + nn) * 2048 + k0 + kg]) = o;
  }
}

// ---------------- 8-phase-style 256x256 GEMM (gemm1) ----------------
#define COMPUTE_PAIR(q)                                                              \
  {                                                                                  \
    bf16x8 af[2][2];                                                                 \
    _Pragma("unroll")                                                                \
    for (int m2 = 0; m2 < 2; ++m2)                                                   \
      _Pragma("unroll")                                                              \
      for (int kk = 0; kk < 2; ++kk)                                                 \
        af[m2][kk] = load_frag(&lds[buf][0][wm * 8192 +                              \
            (((q) * 2 + m2) * 16 + l16) * 64 + ((kk * 4 + lg) ^ (l16 & 7)) * 8]);    \
    __builtin_amdgcn_s_setprio(1);                                                   \
    _Pragma("unroll")                                                                \
    for (int m2 = 0; m2 < 2; ++m2)                                                   \
      _Pragma("unroll")                                                              \
      for (int ni = 0; ni < 4; ++ni)                                                 \
        _Pragma("unroll")                                                            \
        for (int kk = 0; kk < 2; ++kk)                                               \
          acc[(q) * 2 + m2][ni] = __builtin_amdgcn_mfma_f32_16x16x32_bf16(           \
              af[m2][kk], bper[ni][kk], acc[(q) * 2 + m2][ni], 0, 0, 0);             \
    __builtin_amdgcn_s_setprio(0);                                                   \
  }

template <bool BF16OUT>
__global__ __launch_bounds__(512, 2) void gemm8p_kernel(const u16* __restrict__ A,
                                                        const u16* __restrict__ BT,
                                                        void* __restrict__ Cp,
                                                        int M, int N, int K, int gx) {
  __shared__ u16 lds[2][2][16384];   // [buf][A/B][256 rows x 64] = 128 KiB
  const int tid = threadIdx.x;
  const int wave = tid >> 6, lane = tid & 63;
  const int l16 = lane & 15, lg = lane >> 4;
  const int wm = wave >> 2, wn = wave & 3;
  const int rloc = lane >> 3;
  const int sOff = ((lane & 7) ^ rloc) * 8;
  const int nwg = gridDim.x;
  const int swz = (blockIdx.x & 7) * (nwg >> 3) + (blockIdx.x >> 3);
  const int bm = (swz / gx) * 256, bn = (swz % gx) * 256;

  f32x4 acc[8][4] = {};

  auto stage = [&](int dstbuf, int x, int h, const u16* xp, int xr0, int kk0) {
#pragma unroll
    for (int j = 0; j < 2; ++j) {
      int c = j * 8 + wave;   // 0..15, 1KB chunk = 8 rows
      async16(&lds[dstbuf][x][h * 8192 + c * 512],
              xp + (size_t)(xr0 + h * 128 + c * 8 + rloc) * K + kk0 + sOff);
    }
  };

  stage(0, 0, 0, A, bm, 0);
  stage(0, 0, 1, A, bm, 0);
  stage(0, 1, 0, BT, bn, 0);
  stage(0, 1, 1, BT, bn, 0);

  const int NT = K >> 6;
  for (int kt = 0; kt < NT; ++kt) {
    const int buf = kt & 1, nbuf = buf ^ 1;
    const int k0n = (kt + 1) << 6;
    const bool pf = (kt + 1 < NT);
    bf16x8 bper[4][2];

    if (pf) {
      stage(nbuf, 0, 0, A, bm, k0n);
      asm volatile("s_waitcnt vmcnt(2)" ::: "memory");
    } else {
      asm volatile("s_waitcnt vmcnt(0)" ::: "memory");
    }
    __builtin_amdgcn_s_barrier();
    __builtin_amdgcn_sched_barrier(0);
#pragma unroll
    for (int ni = 0; ni < 4; ++ni)
#pragma unroll
      for (int kk = 0; kk < 2; ++kk)
        bper[ni][kk] = load_frag(&lds[buf][1][(wn >> 1) * 8192 +
            ((wn & 1) * 64 + ni * 16 + l16) * 64 + ((kk * 4 + lg) ^ (l16 & 7)) * 8]);
    COMPUTE_PAIR(0)
    if (pf) stage(nbuf, 0, 1, A, bm, k0n);
    __builtin_amdgcn_s_barrier();
    __builtin_amdgcn_sched_barrier(0);
    COMPUTE_PAIR(1)
    if (pf) stage(nbuf, 1, 0, BT, bn, k0n);
    __builtin_amdgcn_s_barrier();
    __builtin_amdgcn_sched_barrier(0);
    COMPUTE_PAIR(2)
    if (pf) stage(nbuf, 1, 1, BT, bn, k0n);
    __builtin_amdgcn_s_barrier();
    __builtin_amdgcn_sched_barrier(0);
    COMPUTE_PAIR(3)
    __builtin_amdgcn_s_barrier();
  }

#pragma unroll
  for (int mi = 0; mi < 8; ++mi)
#pragma unroll
    for (int ni = 0; ni < 4; ++ni)
#pragma unroll
      for (int r = 0; r < 4; ++r) {
        size_t idx = (size_t)(bm + wm * 128 + mi * 16 + lg * 4 + r) * N +
                     bn + wn * 64 + ni * 16 + l16;
        if (BF16OUT) ((u16*)Cp)[idx] = f2bf(acc[mi][ni][r]);
        else         ((float*)Cp)[idx] = acc[mi][ni][r];
      }
}

// ---------------- 8-phase-style 256x128 GEMM (gemm2, fp32 out) ----------------
#define COMPUTE_MB(q)                                                                \
  {                                                                                  \
    bf16x8 af[2];                                                                    \
    _Pragma("unroll")                                                                \
    for (int kk = 0; kk < 2; ++kk)                                                   \
      af[kk] = load_frag(&lds2[buf][(wm * 64 + (q) * 16 + l16) * 64 +                \
                                    ((kk * 4 + lg) ^ (l16 & 7)) * 8]);               \
    __builtin_amdgcn_s_setprio(1);                                                   \
    _Pragma("unroll")                                                                \
    for (int ni = 0; ni < 4; ++ni)                                                   \
      _Pragma("unroll")                                                              \
      for (int kk = 0; kk < 2; ++kk)                                                 \
        acc[(q)][ni] = __builtin_amdgcn_mfma_f32_16x16x32_bf16(                      \
            af[kk], bper[ni][kk], acc[(q)][ni], 0, 0, 0);                            \
    __builtin_amdgcn_s_setprio(0);                                                   \
  }

__global__ __launch_bounds__(512, 2) void gemm8p_n128_kernel(const u16* __restrict__ A,
                                                             const u16* __restrict__ BT,
                                                             float* __restrict__ C,
                                                             int M, int N, int K, int gx) {
  __shared__ u16 lds2[2][24576];   // [buf][A 256x64 | B 128x64] = 96 KiB
  const int tid = threadIdx.x;
  const int wave = tid >> 6, lane = tid & 63;
  const int l16 = lane & 15, lg = lane >> 4;
  const int wm = wave >> 1, wn = wave & 1;
  const int rloc = lane >> 3;
  const int sOff = ((lane & 7) ^ rloc) * 8;
  const int nwg = gridDim.x;
  const int swz = (blockIdx.x & 7) * (nwg >> 3) + (blockIdx.x >> 3);
  const int bm = (swz / gx) * 256, bn = (swz % gx) * 128;

  f32x4 acc[4][4] = {};

  auto stageA = [&](int dstbuf, int h, int kk0) {
#pragma unroll
    for (int j = 0; j < 2; ++j) {
      int c = j * 8 + wave;
      async16(&lds2[dstbuf][h * 8192 + c * 512],
              A + (size_t)(bm + h * 128 + c * 8 + rloc) * K + kk0 + sOff);
    }
  };
  auto stageB = [&](int dstbuf, int kk0) {
#pragma unroll
    for (int j = 0; j < 2; ++j) {
      int c = j * 8 + wave;
      async16(&lds2[dstbuf][16384 + c * 512],
              BT + (size_t)(bn + c * 8 + rloc) * K + kk0 + sOff);
    }
  };

  stageA(0, 0, 0);
  stageA(0, 1, 0);
  stageB(0, 0);

  const int NT = K >> 6;
  for (int kt = 0; kt < NT; ++kt) {
    const int buf = kt & 1, nbuf = buf ^ 1;
    const int k0n = (kt + 1) << 6;
    const bool pf = (kt + 1 < NT);
    bf16x8 bper[4][2];

    if (pf) {
      stageA(nbuf, 0, k0n);
      asm volatile("s_waitcnt vmcnt(2)" ::: "memory");
    } else {
      asm volatile("s_waitcnt vmcnt(0)" ::: "memory");
    }
    __builtin_amdgcn_s_barrier();
    __builtin_amdgcn_sched_barrier(0);
#pragma unroll
    for (int ni = 0; ni < 4; ++ni)
#pragma unroll
      for (int kk = 0; kk < 2; ++kk)
        bper[ni][kk] = load_frag(&lds2[buf][16384 +
            (wn * 64 + ni * 16 + l16) * 64 + ((kk * 4 + lg) ^ (l16 & 7)) * 8]);
    COMPUTE_MB(0)
    if (pf) stageA(nbuf, 1, k0n);
    __builtin_amdgcn_s_barrier();
    __builtin_amdgcn_sched_barrier(0);
    COMPUTE_MB(1)
    if (pf) stageB(nbuf, k0n);
    __builtin_amdgcn_s_barrier();
    __builtin_amdgcn_sched_barrier(0);
    COMPUTE_MB(2)
    __builtin_amdgcn_s_barrier();
    __builtin_amdgcn_sched_barrier(0);
    COMPUTE_MB(3)
    __builtin_amdgcn_s_barrier();
  }

#pragma unroll
  for (int mb = 0; mb < 4; ++mb)
#pragma unroll
    for (int ni = 0; ni < 4; ++ni)
#pragma unroll
      for (int r = 0; r < 4; ++r)
        C[(size_t)(bm + wm * 64 + mb * 16 + lg * 4 + r) * N +
          bn + wn * 64 + ni * 16 + l16] = acc[mb][ni][r];
}

// ---------------- RoPE + pack K only (bf16 in / bf16 out) ----------------
__global__ void rope_k_kernel(const u16* __restrict__ qkv, const float* __restrict__ fc,
                              const float* __restrict__ fs, u16* __restrict__ Kb) {
  int gi = blockIdx.x * blockDim.x + threadIdx.x; // (b*SEQ+s)*64 + i
  int i = gi & 63;
  int t = gi >> 6;          // b*SEQ + s
  int s = t & (SEQ - 1), b = t >> 11;
  int kh = blockIdx.y;
  float c = fc[s * 64 + i], sn = fs[s * 64 + i];
  uint32_t pr = *reinterpret_cast<const uint32_t*>(&qkv[(size_t)t * NQKV + NH * HD + kh * HD + 2 * i]);
  float tr = bf2f((u16)(pr & 0xffff)), ti = bf2f((u16)(pr >> 16));
  uint32_t w = (uint32_t)f2bf(tr * c - ti * sn) |
               ((uint32_t)f2bf(tr * sn + ti * c) << 16);
  *reinterpret_cast<uint32_t*>(&Kb[((size_t)(b * NKV + kh) * SEQ + s) * HD + 2 * i]) = w;
}

// ---------------- V transpose: qkv v-part [s][d] bf16 -> VT [d][s] bf16 ----------------
__global__ __launch_bounds__(1024) void vtrans_kernel(const u16* __restrict__ qkv,
                                                      u16* __restrict__ vt) {
  __shared__ u16 t[32][33];
  int s0 = blockIdx.x * 32, d0 = blockIdx.y * 32;
  int bk = blockIdx.z;
  int b = bk >> 2, kh = bk & 3;
  int tx = threadIdx.x, ty = threadIdx.y;
  t[ty][tx] = qkv[(size_t)(b * SEQ + s0 + ty) * NQKV + NH * HD + NKV * HD + kh * HD + d0 + tx];
  __syncthreads();
  vt[((size_t)(b * NKV + kh) * HD + d0 + ty) * SEQ + s0 + tx] = t[tx][ty];
}

// ---------------- causal flash attention (round-10: swapped QK^T + defer-max) --
__global__ __launch_bounds__(256) void attn_kernel(const u16* __restrict__ qkv,
                                                   const float* __restrict__ fc,
                                                   const float* __restrict__ fs,
                                                   const u16* __restrict__ Kc,
                                                   const u16* __restrict__ VT,
                                                   u16* __restrict__ AO) {
  __shared__ u16 Ks[2][64 * 128];   // [key][d], swizzled
  __shared__ u16 Vs[2][128 * 64];   // [d][key], swizzled
  __shared__ u16 Ps[4][16 * 64];    // per-wave P tile [q][key], swizzled
  const int pairi = blockIdx.x;     // 0..15
  const int h = blockIdx.y, b = blockIdx.z;
  const int kvh = h >> 2;
  const int tid = threadIdx.x, wave = tid >> 6, lane = tid & 63;
  const int l16 = lane & 15, lg = lane >> 4;

  const u16* Kbase = Kc + (size_t)(b * NKV + kvh) * SEQ * HD;
  const u16* Vbase = VT + (size_t)(b * NKV + kvh) * HD * SEQ;

  bf16x8 onesf;
#pragma unroll
  for (int j = 0; j < 8; ++j) onesf[j] = __builtin_bit_cast(__bf16, (u16)0x3F80);

  int kOff[4], vOff[4], kDst[4], vDst[4];
#pragma unroll
  for (int i = 0; i < 4; ++i) {
    int chunk = i * 4 + wave;                 // 0..15
    int krow = chunk * 4 + (lane >> 4);       // 0..63
    kOff[i] = krow * HD + ((lane & 15) ^ (krow & 15)) * 8;
    kDst[i] = chunk * 512;
    int vrow = chunk * 8 + (lane >> 3);       // 0..127
    vOff[i] = vrow * SEQ + ((lane & 7) ^ (vrow & 7)) * 8;
    vDst[i] = chunk * 512;
  }

  for (int sel = 0; sel < 2; ++sel) {
    const int qblk = sel ? pairi : (31 - pairi);
    const int qrow0 = qblk * 64 + wave * 16;
    const int rq = qrow0 + l16;     // this lane's q row

    // ---- Q load + in-register RoPE ----
    const float qs = 0.12751689760098266f; // log2(e)/sqrt(128)
    const u16* Qrow = qkv + (size_t)(b * SEQ + rq) * NQKV + h * HD;
    const float* fcb = fc + (size_t)rq * 64;
    const float* fsb = fs + (size_t)rq * 64;
    bf16x8 qf[4];
#pragma unroll
    for (int c = 0; c < 4; ++c) {
      bf16x8 raw = load_frag(Qrow + c * 32 + lg * 8);
      float4 cc = *reinterpret_cast<const float4*>(fcb + c * 16 + lg * 4);
      float4 sv = *reinterpret_cast<const float4*>(fsb + c * 16 + lg * 4);
      bf16x8 q;
#pragma unroll
      for (int j = 0; j < 4; ++j) {
        float e = (float)raw[2 * j], od = (float)raw[2 * j + 1];
        float ce = (&cc.x)[j] * qs, se = (&sv.x)[j] * qs;
        q[2 * j]     = (__bf16)(e * ce - od * se);
        q[2 * j + 1] = (__bf16)(e * se + od * ce);
      }
      qf[c] = q;
    }

    f32x4 o[8] = {};
    f32x4 lsum = {};
    float m = -3e38f;

    __syncthreads(); // all waves done with LDS from previous q-tile
#pragma unroll
    for (int i = 0; i < 4; ++i) {
      async16(&Ks[0][kDst[i]], Kbase + kOff[i]);
      async16(&Vs[0][vDst[i]], Vbase + vOff[i]);
    }

    for (int kt = 0; kt <= qblk; ++kt) {
      const int cur = kt & 1;
      __syncthreads(); // tile kt staged; all waves done with buf[cur]
      if (kt < qblk) {
        const int k0n = (kt + 1) * 64;
#pragma unroll
        for (int i = 0; i < 4; ++i) {
          async16(&Ks[cur ^ 1][kDst[i]], Kbase + (size_t)k0n * HD + kOff[i]);
          async16(&Vs[cur ^ 1][vDst[i]], Vbase + k0n + vOff[i]);
        }
      }

      // QK^T swapped: s[cb][r] = S[key = k0+cb*16+lg*4+r][q = l16]
      f32x4 s[4] = {};
      __builtin_amdgcn_s_setprio(1);
#pragma unroll
      for (int cb = 0; cb < 4; ++cb) {
#pragma unroll
        for (int c = 0; c < 4; ++c) {
          bf16x8 kf = load_frag(&Ks[cur][(cb * 16 + l16) * 128 + (((c * 4 + lg) ^ l16) & 15) * 8]);
          s[cb] = __builtin_amdgcn_mfma_f32_16x16x32_bf16(kf, qf[c], s[cb], 0, 0, 0);
        }
      }
      __builtin_amdgcn_s_setprio(0);

      if (kt == qblk) { // diagonal tile: causal mask
        const int k0 = kt * 64;
#pragma unroll
        for (int cb = 0; cb < 4; ++cb) {
#pragma unroll
          for (int r = 0; r < 4; ++r) {
            int key = k0 + cb * 16 + lg * 4 + r;
            if (key > rq) s[cb][r] = -1e30f;
          }
        }
      }

      // per-lane tile max (q = l16)
      float v0 = fmaxf(fmaxf(fmaxf(s[0][0], s[0][1]), fmaxf(s[0][2], s[0][3])),
                       fmaxf(fmaxf(s[1][0], s[1][1]), fmaxf(s[1][2], s[1][3])));
      v0 = fmaxf(v0, fmaxf(fmaxf(fmaxf(s[2][0], s[2][1]), fmaxf(s[2][2], s[2][3])),
                           fmaxf(fmaxf(s[3][0], s[3][1]), fmaxf(s[3][2], s[3][3]))));
      v0 = fmaxf(v0, __shfl_xor(v0, 16));
      v0 = fmaxf(v0, __shfl_xor(v0, 32));

      bool need = v0 > m + 8.f;
      if (__any(need)) {
        float newm = fmaxf(m, v0);
        float sc = exp2f(m - newm);
        m = newm;
        float scR[4];
#pragma unroll
        for (int r = 0; r < 4; ++r) scR[r] = __shfl(sc, lg * 4 + r);
#pragma unroll
        for (int r = 0; r < 4; ++r) {
          lsum[r] *= scR[r];
#pragma unroll
          for (int db = 0; db < 8; ++db) o[db][r] *= scR[r];
        }
      }

      // exp2 + pack + one b64 write per cb (keys cb*16+lg*4..+3, row q=l16)
#pragma unroll
      for (int cb = 0; cb < 4; ++cb) {
        uint32_t lo = (uint32_t)f2bf(exp2f(s[cb][0] - m)) |
                      ((uint32_t)f2bf(exp2f(s[cb][1] - m)) << 16);
        uint32_t hi = (uint32_t)f2bf(exp2f(s[cb][2] - m)) |
                      ((uint32_t)f2bf(exp2f(s[cb][3] - m)) << 16);
        int idx = (l16 * 64 + cb * 16 + lg * 4) ^ ((l16 & 7) << 3);
        uint64_t w = (uint64_t)lo | ((uint64_t)hi << 32);
        *reinterpret_cast<uint64_t*>(&Ps[wave][idx]) = w;
      }

      bf16x8 pf[2];
#pragma unroll
      for (int c = 0; c < 2; ++c)
        pf[c] = load_frag(&Ps[wave][(l16 * 64 + c * 32 + lg * 8) ^ ((l16 & 7) << 3)]);
      __builtin_amdgcn_s_setprio(1);
#pragma unroll
      for (int c = 0; c < 2; ++c)
        lsum = __builtin_amdgcn_mfma_f32_16x16x32_bf16(pf[c], onesf, lsum, 0, 0, 0);
#pragma unroll
      for (int db = 0; db < 8; ++db) {
#pragma unroll
        for (int c = 0; c < 2; ++c) {
          bf16x8 vf = load_frag(&Vs[cur][(db * 16 + l16) * 64 + ((c * 4 + lg) ^ (l16 & 7)) * 8]);
          o[db] = __builtin_amdgcn_mfma_f32_16x16x32_bf16(pf[c], vf, o[db], 0, 0, 0);
        }
      }
      __builtin_amdgcn_s_setprio(0);
    }

#pragma unroll
    for (int r = 0; r < 4; ++r) {
      float inv = 1.f / lsum[r];
      int rqo = qrow0 + lg * 4 + r;
      size_t dst = ((size_t)(b * SEQ + rqo) * NH + h) * HD;
#pragma unroll
      for (int db = 0; db < 8; ++db)
        AO[dst + db * 16 + l16] = f2bf(o[db][r] * inv);
    }
  }
}

extern "C" void kernel_launch(void* const* d_in, const int* in_sizes, int n_in,
                              void* d_out, int out_size, void* d_ws, size_t ws_size,
                              hipStream_t stream) {
  (void)in_sizes; (void)n_in; (void)out_size; (void)ws_size;
  const float* x  = (const float*)d_in[0];
  const float* fc = (const float*)d_in[1];
  const float* fs = (const float*)d_in[2];
  const float* wq = (const float*)d_in[3];
  const float* wk = (const float*)d_in[4];
  const float* wv = (const float*)d_in[5];
  const float* wo = (const float*)d_in[6];
  float* out = (float*)d_out;

  char* ws = (char*)d_ws;
  u16*  xb    = (u16*)(ws);                      // 16,777,216
  u16*  wtqkv = (u16*)(ws + 16777216);           // 12,582,912
  u16*  wto   = (u16*)(ws + 29360128);           //  8,388,608
  u16*  qkv   = (u16*)(ws + 37748736);           // 25,165,824 (bf16)
  u16*  Kb    = (u16*)(ws + 62914560);           //  4,194,304
  u16*  VTb   = (u16*)(ws + 67108864);           //  4,194,304
  u16*  AOb   = (u16*)(ws + 71303168);           // 16,777,216

  cast_x_kernel<<<dim3(8192), dim3(256), 0, stream>>>(x, xb);
  wtrans64_kernel<<<dim3(32, 80), dim3(256), 0, stream>>>(wq, wk, wv, wo, wtqkv, wto);

  gemm8p_kernel<true><<<dim3(192), dim3(512), 0, stream>>>(xb, wtqkv, qkv, MROWS, NQKV, DIMSZ, 12);

  rope_k_kernel<<<dim3(1024, 4), dim3(256), 0, stream>>>(qkv, fc, fs, Kb);
  vtrans_kernel<<<dim3(64, 4, 8), dim3(32, 32), 0, stream>>>(qkv, VTb);

  attn_kernel<<<dim3(16, 16, 2), dim3(256), 0, stream>>>(qkv, fc, fs, Kb, VTb, AOb);

  gemm8p_n128_kernel<<<dim3(256), dim3(512), 0, stream>>>(AOb, wto, out, MROWS, DIMSZ, DIMSZ, 16);
}

// Round 15
// 193.318 us; speedup vs baseline: 1.2623x; 1.0211x over previous
//
#include <hip/hip_runtime.h>
#include <stdint.h>

#define DIMSZ 2048
#define NH 16
#define NKV 4
#define HD 128
#define BATCH 2
#define SEQ 2048
#define MROWS (BATCH*SEQ)          // 4096
#define NQKV (NH*HD + 2*NKV*HD)    // 3072

typedef unsigned short u16;
typedef float f32x4 __attribute__((ext_vector_type(4)));
typedef short short8 __attribute__((ext_vector_type(8)));
typedef __bf16 bf16x8 __attribute__((ext_vector_type(8)));
typedef unsigned short u16x4 __attribute__((ext_vector_type(4)));
typedef unsigned short u16x8 __attribute__((ext_vector_type(8)));

__device__ __forceinline__ u16 f2bf(float f) {
  __bf16 h = (__bf16)f;           // native RNE convert
  return __builtin_bit_cast(u16, h);
}

__device__ __forceinline__ float bf2f(u16 h) {
  union { uint32_t u; float f; } v; v.u = ((uint32_t)h) << 16; return v.f;
}

__device__ __forceinline__ void async16(void* lds, const void* g) {
  __builtin_amdgcn_global_load_lds(
      (const __attribute__((address_space(1))) void*)(g),
      (__attribute__((address_space(3))) void*)(lds), 16, 0, 0);
}

__device__ __forceinline__ bf16x8 load_frag(const u16* p) {
  short8 v = *reinterpret_cast<const short8*>(p);
  return __builtin_bit_cast(bf16x8, v);
}

// ------------- prep: x cast + merged transpose-cast of all 4 weights -------------
// grid (32, 336), 256 threads. y<80: wtrans64 (y<32 wq | y<40 wk | y<48 wv |
// y<80 wo); y>=80: x fp32->bf16 cast, flat block id = (y-80)*32 + x (8192 blocks).
__global__ __launch_bounds__(256) void prep_kernel(const float* __restrict__ x,
                                                   const float* __restrict__ wq,
                                                   const float* __restrict__ wk,
                                                   const float* __restrict__ wv,
                                                   const float* __restrict__ wo,
                                                   u16* __restrict__ xb,
                                                   u16* __restrict__ wtqkv,
                                                   u16* __restrict__ wto) {
  __shared__ float tb[64][65];
  int y = blockIdx.y;
  if (y >= 80) {                 // ---- x cast branch ----
    int id = (y - 80) * 32 + blockIdx.x;            // 0..8191
    int i = (id * 256 + (int)threadIdx.x) * 4;
    float4 v = *reinterpret_cast<const float4*>(x + i);
    u16x4 o;
    o.x = f2bf(v.x); o.y = f2bf(v.y); o.z = f2bf(v.z); o.w = f2bf(v.w);
    *reinterpret_cast<u16x4*>(xb + i) = o;
    return;
  }
  // ---- weight transpose branch: 64x64 tiles, float4 loads, u16x8 stores ----
  const float* src; int srcN; u16* dst; int nbase;
  if (y < 32)      { src = wq; srcN = 2048; dst = wtqkv;                        nbase = y * 64; }
  else if (y < 40) { src = wk; srcN = 512;  dst = wtqkv + (size_t)2048 * 2048;  nbase = (y - 32) * 64; }
  else if (y < 48) { src = wv; srcN = 512;  dst = wtqkv + (size_t)2560 * 2048;  nbase = (y - 40) * 64; }
  else             { src = wo; srcN = 2048; dst = wto;                          nbase = (y - 48) * 64; }
  int k0 = blockIdx.x * 64;
  int t = threadIdx.x;
  int lr = t >> 4, lc = (t & 15) * 4;
#pragma unroll
  for (int i = 0; i < 4; ++i) {
    int row = lr + i * 16;
    float4 v = *reinterpret_cast<const float4*>(&src[(size_t)(k0 + row) * srcN + nbase + lc]);
    tb[row][lc] = v.x; tb[row][lc + 1] = v.y; tb[row][lc + 2] = v.z; tb[row][lc + 3] = v.w;
  }
  __syncthreads();
  int n = t >> 3, kg = (t & 7) * 8;
#pragma unroll
  for (int i = 0; i < 2; ++i) {
    int nn = n + i * 32;
    u16x8 o;
#pragma unroll
    for (int j = 0; j < 8; ++j) o[j] = f2bf(tb[kg + j][nn]);
    *reinterpret_cast<u16x8*>(&dst[(size_t)(nbase + nn) * 2048 + k0 + kg]) = o;
  }
}

// ---------------- 8-phase-style 256x256 GEMM (gemm1) ----------------
#define COMPUTE_PAIR(q)                                                              \
  {                                                                                  \
    bf16x8 af[2][2];                                                                 \
    _Pragma("unroll")                                                                \
    for (int m2 = 0; m2 < 2; ++m2)                                                   \
      _Pragma("unroll")                                                              \
      for (int kk = 0; kk < 2; ++kk)                                                 \
        af[m2][kk] = load_frag(&lds[buf][0][wm * 8192 +                              \
            (((q) * 2 + m2) * 16 + l16) * 64 + ((kk * 4 + lg) ^ (l16 & 7)) * 8]);    \
    __builtin_amdgcn_s_setprio(1);                                                   \
    _Pragma("unroll")                                                                \
    for (int m2 = 0; m2 < 2; ++m2)                                                   \
      _Pragma("unroll")                                                              \
      for (int ni = 0; ni < 4; ++ni)                                                 \
        _Pragma("unroll")                                                            \
        for (int kk = 0; kk < 2; ++kk)                                               \
          acc[(q) * 2 + m2][ni] = __builtin_amdgcn_mfma_f32_16x16x32_bf16(           \
              af[m2][kk], bper[ni][kk], acc[(q) * 2 + m2][ni], 0, 0, 0);             \
    __builtin_amdgcn_s_setprio(0);                                                   \
  }

template <bool BF16OUT>
__global__ __launch_bounds__(512, 2) void gemm8p_kernel(const u16* __restrict__ A,
                                                        const u16* __restrict__ BT,
                                                        void* __restrict__ Cp,
                                                        int M, int N, int K, int gx) {
  __shared__ u16 lds[2][2][16384];   // [buf][A/B][256 rows x 64] = 128 KiB
  const int tid = threadIdx.x;
  const int wave = tid >> 6, lane = tid & 63;
  const int l16 = lane & 15, lg = lane >> 4;
  const int wm = wave >> 2, wn = wave & 3;
  const int rloc = lane >> 3;
  const int sOff = ((lane & 7) ^ rloc) * 8;
  const int nwg = gridDim.x;
  const int swz = (blockIdx.x & 7) * (nwg >> 3) + (blockIdx.x >> 3);
  const int bm = (swz / gx) * 256, bn = (swz % gx) * 256;

  f32x4 acc[8][4] = {};

  auto stage = [&](int dstbuf, int x, int h, const u16* xp, int xr0, int kk0) {
#pragma unroll
    for (int j = 0; j < 2; ++j) {
      int c = j * 8 + wave;   // 0..15, 1KB chunk = 8 rows
      async16(&lds[dstbuf][x][h * 8192 + c * 512],
              xp + (size_t)(xr0 + h * 128 + c * 8 + rloc) * K + kk0 + sOff);
    }
  };

  stage(0, 0, 0, A, bm, 0);
  stage(0, 0, 1, A, bm, 0);
  stage(0, 1, 0, BT, bn, 0);
  stage(0, 1, 1, BT, bn, 0);

  const int NT = K >> 6;
  for (int kt = 0; kt < NT; ++kt) {
    const int buf = kt & 1, nbuf = buf ^ 1;
    const int k0n = (kt + 1) << 6;
    const bool pf = (kt + 1 < NT);
    bf16x8 bper[4][2];

    if (pf) {
      stage(nbuf, 0, 0, A, bm, k0n);
      asm volatile("s_waitcnt vmcnt(2)" ::: "memory");
    } else {
      asm volatile("s_waitcnt vmcnt(0)" ::: "memory");
    }
    __builtin_amdgcn_s_barrier();
    __builtin_amdgcn_sched_barrier(0);
#pragma unroll
    for (int ni = 0; ni < 4; ++ni)
#pragma unroll
      for (int kk = 0; kk < 2; ++kk)
        bper[ni][kk] = load_frag(&lds[buf][1][(wn >> 1) * 8192 +
            ((wn & 1) * 64 + ni * 16 + l16) * 64 + ((kk * 4 + lg) ^ (l16 & 7)) * 8]);
    COMPUTE_PAIR(0)
    if (pf) stage(nbuf, 0, 1, A, bm, k0n);
    __builtin_amdgcn_s_barrier();
    __builtin_amdgcn_sched_barrier(0);
    COMPUTE_PAIR(1)
    if (pf) stage(nbuf, 1, 0, BT, bn, k0n);
    __builtin_amdgcn_s_barrier();
    __builtin_amdgcn_sched_barrier(0);
    COMPUTE_PAIR(2)
    if (pf) stage(nbuf, 1, 1, BT, bn, k0n);
    __builtin_amdgcn_s_barrier();
    __builtin_amdgcn_sched_barrier(0);
    COMPUTE_PAIR(3)
    __builtin_amdgcn_s_barrier();
  }

#pragma unroll
  for (int mi = 0; mi < 8; ++mi)
#pragma unroll
    for (int ni = 0; ni < 4; ++ni)
#pragma unroll
      for (int r = 0; r < 4; ++r) {
        size_t idx = (size_t)(bm + wm * 128 + mi * 16 + lg * 4 + r) * N +
                     bn + wn * 64 + ni * 16 + l16;
        if (BF16OUT) ((u16*)Cp)[idx] = f2bf(acc[mi][ni][r]);
        else         ((float*)Cp)[idx] = acc[mi][ni][r];
      }
}

// ---------------- 8-phase-style 256x128 GEMM (gemm2, fp32 out) ----------------
#define COMPUTE_MB(q)                                                                \
  {                                                                                  \
    bf16x8 af[2];                                                                    \
    _Pragma("unroll")                                                                \
    for (int kk = 0; kk < 2; ++kk)                                                   \
      af[kk] = load_frag(&lds2[buf][(wm * 64 + (q) * 16 + l16) * 64 +                \
                                    ((kk * 4 + lg) ^ (l16 & 7)) * 8]);               \
    __builtin_amdgcn_s_setprio(1);                                                   \
    _Pragma("unroll")                                                                \
    for (int ni = 0; ni < 4; ++ni)                                                   \
      _Pragma("unroll")                                                              \
      for (int kk = 0; kk < 2; ++kk)                                                 \
        acc[(q)][ni] = __builtin_amdgcn_mfma_f32_16x16x32_bf16(                      \
            af[kk], bper[ni][kk], acc[(q)][ni], 0, 0, 0);                            \
    __builtin_amdgcn_s_setprio(0);                                                   \
  }

__global__ __launch_bounds__(512, 2) void gemm8p_n128_kernel(const u16* __restrict__ A,
                                                             const u16* __restrict__ BT,
                                                             float* __restrict__ C,
                                                             int M, int N, int K, int gx) {
  __shared__ u16 lds2[2][24576];   // [buf][A 256x64 | B 128x64] = 96 KiB
  const int tid = threadIdx.x;
  const int wave = tid >> 6, lane = tid & 63;
  const int l16 = lane & 15, lg = lane >> 4;
  const int wm = wave >> 1, wn = wave & 1;
  const int rloc = lane >> 3;
  const int sOff = ((lane & 7) ^ rloc) * 8;
  const int nwg = gridDim.x;
  const int swz = (blockIdx.x & 7) * (nwg >> 3) + (blockIdx.x >> 3);
  const int bm = (swz / gx) * 256, bn = (swz % gx) * 128;

  f32x4 acc[4][4] = {};

  auto stageA = [&](int dstbuf, int h, int kk0) {
#pragma unroll
    for (int j = 0; j < 2; ++j) {
      int c = j * 8 + wave;
      async16(&lds2[dstbuf][h * 8192 + c * 512],
              A + (size_t)(bm + h * 128 + c * 8 + rloc) * K + kk0 + sOff);
    }
  };
  auto stageB = [&](int dstbuf, int kk0) {
#pragma unroll
    for (int j = 0; j < 2; ++j) {
      int c = j * 8 + wave;
      async16(&lds2[dstbuf][16384 + c * 512],
              BT + (size_t)(bn + c * 8 + rloc) * K + kk0 + sOff);
    }
  };

  stageA(0, 0, 0);
  stageA(0, 1, 0);
  stageB(0, 0);

  const int NT = K >> 6;
  for (int kt = 0; kt < NT; ++kt) {
    const int buf = kt & 1, nbuf = buf ^ 1;
    const int k0n = (kt + 1) << 6;
    const bool pf = (kt + 1 < NT);
    bf16x8 bper[4][2];

    if (pf) {
      stageA(nbuf, 0, k0n);
      asm volatile("s_waitcnt vmcnt(2)" ::: "memory");
    } else {
      asm volatile("s_waitcnt vmcnt(0)" ::: "memory");
    }
    __builtin_amdgcn_s_barrier();
    __builtin_amdgcn_sched_barrier(0);
#pragma unroll
    for (int ni = 0; ni < 4; ++ni)
#pragma unroll
      for (int kk = 0; kk < 2; ++kk)
        bper[ni][kk] = load_frag(&lds2[buf][16384 +
            (wn * 64 + ni * 16 + l16) * 64 + ((kk * 4 + lg) ^ (l16 & 7)) * 8]);
    COMPUTE_MB(0)
    if (pf) stageA(nbuf, 1, k0n);
    __builtin_amdgcn_s_barrier();
    __builtin_amdgcn_sched_barrier(0);
    COMPUTE_MB(1)
    if (pf) stageB(nbuf, k0n);
    __builtin_amdgcn_s_barrier();
    __builtin_amdgcn_sched_barrier(0);
    COMPUTE_MB(2)
    __builtin_amdgcn_s_barrier();
    __builtin_amdgcn_sched_barrier(0);
    COMPUTE_MB(3)
    __builtin_amdgcn_s_barrier();
  }

#pragma unroll
  for (int mb = 0; mb < 4; ++mb)
#pragma unroll
    for (int ni = 0; ni < 4; ++ni)
#pragma unroll
      for (int r = 0; r < 4; ++r)
        C[(size_t)(bm + wm * 64 + mb * 16 + lg * 4 + r) * N +
          bn + wn * 64 + ni * 16 + l16] = acc[mb][ni][r];
}

// ------------- rv: RoPE-K pack + V transpose in one launch -------------
// grid (6144), 256 threads. bid<4096: rope_k (kh = bid>>10); else vtrans
// (vt block id = bid-4096: z=id>>8, s0=((id&255)>>2)*32, d0=(id&3)*32).
__global__ __launch_bounds__(256) void rv_kernel(const u16* __restrict__ qkv,
                                                 const float* __restrict__ fc,
                                                 const float* __restrict__ fs,
                                                 u16* __restrict__ Kb,
                                                 u16* __restrict__ vt) {
  __shared__ u16 t[32][33];
  int bid = blockIdx.x;
  if (bid < 4096) {              // ---- rope K branch ----
    int kh = bid >> 10;
    int gi = (bid & 1023) * 256 + (int)threadIdx.x;   // (b*SEQ+s)*64 + i
    int i = gi & 63;
    int tt = gi >> 6;            // b*SEQ + s
    int s = tt & (SEQ - 1), b = tt >> 11;
    float c = fc[s * 64 + i], sn = fs[s * 64 + i];
    uint32_t pr = *reinterpret_cast<const uint32_t*>(&qkv[(size_t)tt * NQKV + NH * HD + kh * HD + 2 * i]);
    float tr = bf2f((u16)(pr & 0xffff)), ti = bf2f((u16)(pr >> 16));
    uint32_t w = (uint32_t)f2bf(tr * c - ti * sn) |
                 ((uint32_t)f2bf(tr * sn + ti * c) << 16);
    *reinterpret_cast<uint32_t*>(&Kb[((size_t)(b * NKV + kh) * SEQ + s) * HD + 2 * i]) = w;
    return;
  }
  // ---- V transpose branch ----
  int id = bid - 4096;           // 0..2047
  int bk = id >> 8;              // 0..7
  int rem = id & 255;
  int s0 = (rem >> 2) * 32;      // 0..63 -> *32
  int d0 = (rem & 3) * 32;
  int b = bk >> 2, kh = bk & 3;
  int tx = threadIdx.x & 31, ty = threadIdx.x >> 5;   // ty 0..7
#pragma unroll
  for (int i = 0; i < 4; ++i) {
    int row = ty + i * 8;
    t[row][tx] = qkv[(size_t)(b * SEQ + s0 + row) * NQKV + NH * HD + NKV * HD + kh * HD + d0 + tx];
  }
  __syncthreads();
#pragma unroll
  for (int i = 0; i < 4; ++i) {
    int row = ty + i * 8;
    vt[((size_t)(b * NKV + kh) * HD + d0 + row) * SEQ + s0 + tx] = t[tx][row];
  }
}

// ---------------- causal flash attention (round-10: swapped QK^T + defer-max) --
__global__ __launch_bounds__(256) void attn_kernel(const u16* __restrict__ qkv,
                                                   const float* __restrict__ fc,
                                                   const float* __restrict__ fs,
                                                   const u16* __restrict__ Kc,
                                                   const u16* __restrict__ VT,
                                                   u16* __restrict__ AO) {
  __shared__ u16 Ks[2][64 * 128];   // [key][d], swizzled
  __shared__ u16 Vs[2][128 * 64];   // [d][key], swizzled
  __shared__ u16 Ps[4][16 * 64];    // per-wave P tile [q][key], swizzled
  const int pairi = blockIdx.x;     // 0..15
  const int h = blockIdx.y, b = blockIdx.z;
  const int kvh = h >> 2;
  const int tid = threadIdx.x, wave = tid >> 6, lane = tid & 63;
  const int l16 = lane & 15, lg = lane >> 4;

  const u16* Kbase = Kc + (size_t)(b * NKV + kvh) * SEQ * HD;
  const u16* Vbase = VT + (size_t)(b * NKV + kvh) * HD * SEQ;

  bf16x8 onesf;
#pragma unroll
  for (int j = 0; j < 8; ++j) onesf[j] = __builtin_bit_cast(__bf16, (u16)0x3F80);

  int kOff[4], vOff[4], kDst[4], vDst[4];
#pragma unroll
  for (int i = 0; i < 4; ++i) {
    int chunk = i * 4 + wave;                 // 0..15
    int krow = chunk * 4 + (lane >> 4);       // 0..63
    kOff[i] = krow * HD + ((lane & 15) ^ (krow & 15)) * 8;
    kDst[i] = chunk * 512;
    int vrow = chunk * 8 + (lane >> 3);       // 0..127
    vOff[i] = vrow * SEQ + ((lane & 7) ^ (vrow & 7)) * 8;
    vDst[i] = chunk * 512;
  }

  for (int sel = 0; sel < 2; ++sel) {
    const int qblk = sel ? pairi : (31 - pairi);
    const int qrow0 = qblk * 64 + wave * 16;
    const int rq = qrow0 + l16;     // this lane's q row

    // ---- Q load + in-register RoPE ----
    const float qs = 0.12751689760098266f; // log2(e)/sqrt(128)
    const u16* Qrow = qkv + (size_t)(b * SEQ + rq) * NQKV + h * HD;
    const float* fcb = fc + (size_t)rq * 64;
    const float* fsb = fs + (size_t)rq * 64;
    bf16x8 qf[4];
#pragma unroll
    for (int c = 0; c < 4; ++c) {
      bf16x8 raw = load_frag(Qrow + c * 32 + lg * 8);
      float4 cc = *reinterpret_cast<const float4*>(fcb + c * 16 + lg * 4);
      float4 sv = *reinterpret_cast<const float4*>(fsb + c * 16 + lg * 4);
      bf16x8 q;
#pragma unroll
      for (int j = 0; j < 4; ++j) {
        float e = (float)raw[2 * j], od = (float)raw[2 * j + 1];
        float ce = (&cc.x)[j] * qs, se = (&sv.x)[j] * qs;
        q[2 * j]     = (__bf16)(e * ce - od * se);
        q[2 * j + 1] = (__bf16)(e * se + od * ce);
      }
      qf[c] = q;
    }

    f32x4 o[8] = {};
    f32x4 lsum = {};
    float m = -3e38f;

    __syncthreads(); // all waves done with LDS from previous q-tile
#pragma unroll
    for (int i = 0; i < 4; ++i) {
      async16(&Ks[0][kDst[i]], Kbase + kOff[i]);
      async16(&Vs[0][vDst[i]], Vbase + vOff[i]);
    }

    for (int kt = 0; kt <= qblk; ++kt) {
      const int cur = kt & 1;
      __syncthreads(); // tile kt staged; all waves done with buf[cur]
      if (kt < qblk) {
        const int k0n = (kt + 1) * 64;
#pragma unroll
        for (int i = 0; i < 4; ++i) {
          async16(&Ks[cur ^ 1][kDst[i]], Kbase + (size_t)k0n * HD + kOff[i]);
          async16(&Vs[cur ^ 1][vDst[i]], Vbase + k0n + vOff[i]);
        }
      }

      // QK^T swapped: s[cb][r] = S[key = k0+cb*16+lg*4+r][q = l16]
      f32x4 s[4] = {};
      __builtin_amdgcn_s_setprio(1);
#pragma unroll
      for (int cb = 0; cb < 4; ++cb) {
#pragma unroll
        for (int c = 0; c < 4; ++c) {
          bf16x8 kf = load_frag(&Ks[cur][(cb * 16 + l16) * 128 + (((c * 4 + lg) ^ l16) & 15) * 8]);
          s[cb] = __builtin_amdgcn_mfma_f32_16x16x32_bf16(kf, qf[c], s[cb], 0, 0, 0);
        }
      }
      __builtin_amdgcn_s_setprio(0);

      if (kt == qblk) { // diagonal tile: causal mask
        const int k0 = kt * 64;
#pragma unroll
        for (int cb = 0; cb < 4; ++cb) {
#pragma unroll
          for (int r = 0; r < 4; ++r) {
            int key = k0 + cb * 16 + lg * 4 + r;
            if (key > rq) s[cb][r] = -1e30f;
          }
        }
      }

      // per-lane tile max (q = l16)
      float v0 = fmaxf(fmaxf(fmaxf(s[0][0], s[0][1]), fmaxf(s[0][2], s[0][3])),
                       fmaxf(fmaxf(s[1][0], s[1][1]), fmaxf(s[1][2], s[1][3])));
      v0 = fmaxf(v0, fmaxf(fmaxf(fmaxf(s[2][0], s[2][1]), fmaxf(s[2][2], s[2][3])),
                           fmaxf(fmaxf(s[3][0], s[3][1]), fmaxf(s[3][2], s[3][3]))));
      v0 = fmaxf(v0, __shfl_xor(v0, 16));
      v0 = fmaxf(v0, __shfl_xor(v0, 32));

      bool need = v0 > m + 8.f;
      if (__any(need)) {
        float newm = fmaxf(m, v0);
        float sc = exp2f(m - newm);
        m = newm;
        float scR[4];
#pragma unroll
        for (int r = 0; r < 4; ++r) scR[r] = __shfl(sc, lg * 4 + r);
#pragma unroll
        for (int r = 0; r < 4; ++r) {
          lsum[r] *= scR[r];
#pragma unroll
          for (int db = 0; db < 8; ++db) o[db][r] *= scR[r];
        }
      }

      // exp2 + pack + one b64 write per cb (keys cb*16+lg*4..+3, row q=l16)
#pragma unroll
      for (int cb = 0; cb < 4; ++cb) {
        uint32_t lo = (uint32_t)f2bf(exp2f(s[cb][0] - m)) |
                      ((uint32_t)f2bf(exp2f(s[cb][1] - m)) << 16);
        uint32_t hi = (uint32_t)f2bf(exp2f(s[cb][2] - m)) |
                      ((uint32_t)f2bf(exp2f(s[cb][3] - m)) << 16);
        int idx = (l16 * 64 + cb * 16 + lg * 4) ^ ((l16 & 7) << 3);
        uint64_t w = (uint64_t)lo | ((uint64_t)hi << 32);
        *reinterpret_cast<uint64_t*>(&Ps[wave][idx]) = w;
      }

      bf16x8 pf[2];
#pragma unroll
      for (int c = 0; c < 2; ++c)
        pf[c] = load_frag(&Ps[wave][(l16 * 64 + c * 32 + lg * 8) ^ ((l16 & 7) << 3)]);
      __builtin_amdgcn_s_setprio(1);
#pragma unroll
      for (int c = 0; c < 2; ++c)
        lsum = __builtin_amdgcn_mfma_f32_16x16x32_bf16(pf[c], onesf, lsum, 0, 0, 0);
#pragma unroll
      for (int db = 0; db < 8; ++db) {
#pragma unroll
        for (int c = 0; c < 2; ++c) {
          bf16x8 vf = load_frag(&Vs[cur][(db * 16 + l16) * 64 + ((c * 4 + lg) ^ (l16 & 7)) * 8]);
          o[db] = __builtin_amdgcn_mfma_f32_16x16x32_bf16(pf[c], vf, o[db], 0, 0, 0);
        }
      }
      __builtin_amdgcn_s_setprio(0);
    }

#pragma unroll
    for (int r = 0; r < 4; ++r) {
      float inv = 1.f / lsum[r];
      int rqo = qrow0 + lg * 4 + r;
      size_t dst = ((size_t)(b * SEQ + rqo) * NH + h) * HD;
#pragma unroll
      for (int db = 0; db < 8; ++db)
        AO[dst + db * 16 + l16] = f2bf(o[db][r] * inv);
    }
  }
}

extern "C" void kernel_launch(void* const* d_in, const int* in_sizes, int n_in,
                              void* d_out, int out_size, void* d_ws, size_t ws_size,
                              hipStream_t stream) {
  (void)in_sizes; (void)n_in; (void)out_size; (void)ws_size;
  const float* x  = (const float*)d_in[0];
  const float* fc = (const float*)d_in[1];
  const float* fs = (const float*)d_in[2];
  const float* wq = (const float*)d_in[3];
  const float* wk = (const float*)d_in[4];
  const float* wv = (const float*)d_in[5];
  const float* wo = (const float*)d_in[6];
  float* out = (float*)d_out;

  char* ws = (char*)d_ws;
  u16*  xb    = (u16*)(ws);                      // 16,777,216
  u16*  wtqkv = (u16*)(ws + 16777216);           // 12,582,912
  u16*  wto   = (u16*)(ws + 29360128);           //  8,388,608
  u16*  qkv   = (u16*)(ws + 37748736);           // 25,165,824 (bf16)
  u16*  Kb    = (u16*)(ws + 62914560);           //  4,194,304
  u16*  VTb   = (u16*)(ws + 67108864);           //  4,194,304
  u16*  AOb   = (u16*)(ws + 71303168);           // 16,777,216

  prep_kernel<<<dim3(32, 336), dim3(256), 0, stream>>>(x, wq, wk, wv, wo, xb, wtqkv, wto);

  gemm8p_kernel<true><<<dim3(192), dim3(512), 0, stream>>>(xb, wtqkv, qkv, MROWS, NQKV, DIMSZ, 12);

  rv_kernel<<<dim3(6144), dim3(256), 0, stream>>>(qkv, fc, fs, Kb, VTb);

  attn_kernel<<<dim3(16, 16, 2), dim3(256), 0, stream>>>(qkv, fc, fs, Kb, VTb, AOb);

  gemm8p_n128_kernel<<<dim3(256), dim3(512), 0, stream>>>(AOb, wto, out, MROWS, DIMSZ, DIMSZ, 16);
}